// Round 8
// baseline (116506.689 us; speedup 1.0000x reference)
//
#include <hip/hip_runtime.h>
#include <math.h>
#include <stdint.h>

#define NN 2048
#define NE 65536
#define ND 5
#define DMX 256
#define MAXB1 2048
#define SUBD 8
#define NBF (MAXB1*SUBD+1)
#define NFMAX 1536
#define MAXRUN 1536
#define NPB 4
#define COARSE_H 1.76f
#define NUDGE 2e-3f
#define THRG 0.5f

typedef float f32x16 __attribute__((ext_vector_type(16)));
typedef short s16x8 __attribute__((ext_vector_type(8)));
typedef unsigned short u16x8 __attribute__((ext_vector_type(8)));

// ============================ device helpers ============================
__device__ __forceinline__ float wredSum(float v){
#pragma unroll
  for (int o=32;o>0;o>>=1) v += __shfl_down(v,o,64);
  return v;
}
__device__ __forceinline__ float wredMin(float v){
#pragma unroll
  for (int o=32;o>0;o>>=1) v = fminf(v,__shfl_down(v,o,64));
  return v;
}
__device__ __forceinline__ float wredMax(float v){
#pragma unroll
  for (int o=32;o>0;o>>=1) v = fmaxf(v,__shfl_down(v,o,64));
  return v;
}
__device__ __forceinline__ uint32_t encF(float f){
  uint32_t u = __float_as_uint(f);
  return (u & 0x80000000u) ? ~u : (u | 0x80000000u);
}
__device__ __forceinline__ float decF(uint32_t u){
  return (u & 0x80000000u) ? __uint_as_float(u ^ 0x80000000u) : __uint_as_float(~u);
}
__device__ __forceinline__ uint16_t bf16hi(float f){
  return (uint16_t)(__float_as_uint(f)>>16);
}

// precompute bf16 hi/lo split of X in chunk-transposed staged layout:
// XPH8[((dim*(NN/8)) + c2)*co + col] = u16x8 of rows c2*8..c2*8+7, column col
__global__ void k_prep(const float* __restrict__ xn, uint16_t* __restrict__ xph,
                       uint16_t* __restrict__ xpl, int co){
  const int dim = blockIdx.y;
  const int c2 = blockIdx.x;           // 0..NN/8-1
  const int col = threadIdx.x;         // 0..co-1
  const float* x = xn + (size_t)dim*NN*co;
  const int kb = c2*8;
  u16x8 h8, l8;
#pragma unroll
  for (int j=0;j<8;j++){
    const float x0 = x[(size_t)(kb+j)*co + col];
    const uint16_t h = bf16hi(x0);
    h8[j] = h;
    l8[j] = bf16hi(x0 - __uint_as_float((uint32_t)h<<16));
  }
  const size_t o = ((size_t)dim*(NN/8) + c2)*co + col;
  reinterpret_cast<u16x8*>(xph)[o] = h8;
  reinterpret_cast<u16x8*>(xpl)[o] = l8;
}

// ============================ nu(t) evaluation (TWO t per block) ==========
// nu(t) = #{eig(L) < t} = #{a_i < t} + n_-( I - X^T diag(1/(a-t)) X )
// Two t-points share: phase-1 passes, x staging (XTh/XTl), B-operand frags,
// all barriers, global xph/xpl traffic. Per-t: pole weights, WA*/WB* staging,
// A-operand frags, 4 MFMA acc chains each (8 total, registers persist while
// the first LDL^T runs -> one M buffer suffices; inertia runs twice).
// Gram: bf16x3 split MFMA (v_mfma_f32_32x32x16_bf16), per-chain operand
// order identical to the single-t version (bitwise-same results).
// Inertia: panel-8 blocked LDL^T; lane0 factors 8x8 block in regs, 64 lanes
// solve trailing rows in parallel; rank-8 trailing update, 2 barriers/panel.
template<int D, int BLK>
__device__ void evalNu2(const uint16_t* __restrict__ xph, const uint16_t* __restrict__ xpl,
                        const float* __restrict__ a,
                        float t0a, float t0b, float dlt,
                        float* M, float* Pt, float* red, float* wrow,
                        float* scal,
                        float* tOutA, float* tOutB, int* nuOutA, int* nuOutB)
{
  const int tid = threadIdx.x;
  float* fsc = scal + 16;   // 48-float panel-factor scratch

  // ---- phase 1a: nudge both t away from poles a_i (one pass) ----
  float md0 = 1e30f, md1 = 1e30f;
  for (int i=tid;i<NN;i+=BLK){
    const float av = a[i];
    md0 = fminf(md0, fabsf(av - t0a));
    md1 = fminf(md1, fabsf(av - t0b));
  }
  md0 = wredMin(md0); md1 = wredMin(md1);
  if ((tid & 63) == 0){ red[tid>>6] = md0; red[16 + (tid>>6)] = md1; }
  __syncthreads();
  if (tid == 0){
    float m0 = 1e30f, m1 = 1e30f;
    for (int i=0;i<BLK/64;i++){ m0 = fminf(m0, red[i]); m1 = fminf(m1, red[16+i]); }
    scal[1] = (m0 < 1e-3f) ? (t0a + dlt) : t0a;
    scal[2] = (m1 < 1e-3f) ? (t0b + dlt) : t0b;
  }
  __syncthreads();
  const float tA = scal[1], tB = scal[2];
  __syncthreads();

  // ---- phase 1b: count a_i < t (both, one pass) ----
  float c0 = 0.f, c1 = 0.f;
  for (int i=tid;i<NN;i+=BLK){
    const float av = a[i];
    c0 += (av < tA) ? 1.f : 0.f;
    c1 += (av < tB) ? 1.f : 0.f;
  }
  c0 = wredSum(c0); c1 = wredSum(c1);
  if ((tid & 63) == 0){ red[tid>>6] = c0; red[16 + (tid>>6)] = c1; }
  __syncthreads();
  if (tid == 0){
    float s0=0.f, s1=0.f;
    for (int i=0;i<BLK/64;i++){ s0 += red[i]; s1 += red[16+i]; }
    red[0] = s0; red[16] = s1;
  }
  __syncthreads();
  const float cntA = red[0], cntB = red[16];
  __syncthreads();

  // ---- phase 2: two Grams via bf16x3 MFMA, shared x staging ----
  constexpr int BG  = D/64;            // 2x2-tile block grid dim
  constexpr int NBL = BG*(BG+1)/2;     // upper-tri blocks == waves
  constexpr int SXT = 24;              // u16 stride: K=16 + pad8 (48B rows)
  static_assert(BLK == NBL*64, "one wave per tile block");
  static_assert(6*D*SXT*2 <= (D*(D+1)/2 + 12*D)*4, "XT overlay fits in M+Pt");

  uint16_t* XTh = reinterpret_cast<uint16_t*>(M);
  uint16_t* XTl = XTh + D*SXT;
  uint16_t* WAh = XTl + D*SXT;
  uint16_t* WAl = WAh + D*SXT;
  uint16_t* WBh = WAl + D*SXT;
  uint16_t* WBl = WBh + D*SXT;
  const u16x8* XPH = reinterpret_cast<const u16x8*>(xph);
  const u16x8* XPL = reinterpret_cast<const u16x8*>(xpl);

  const int wv_ = tid >> 6, lane = tid & 63;
  int bi = 0, bj = 0;
  { int rem = wv_; while (rem >= BG - bi){ rem -= BG - bi; bi++; } bj = bi + rem; }
  const int colA = bi*64 + (lane & 31);
  const int colB = bj*64 + (lane & 31);
  const int kgo  = (lane >> 5) * 8;

  f32x16 accA0, accA1, accA2, accA3, accB0, accB1, accB2, accB3;
#pragma unroll
  for (int e=0;e<16;e++){
    accA0[e]=0.f; accA1[e]=0.f; accA2[e]=0.f; accA3[e]=0.f;
    accB0[e]=0.f; accB1[e]=0.f; accB2[e]=0.f; accB3[e]=0.f;
  }

  // prologue: pole weights for chunk 0 (buffer 0), both t's
  if (tid < 16){
    float den = a[tid] - tA;
    if (fabsf(den) < 1e-5f) den = (den < 0.f) ? -1e-5f : 1e-5f;
    wrow[tid] = 1.0f/den;
  } else if (tid < 32){
    float den = a[tid-16] - tB;
    if (fabsf(den) < 1e-5f) den = (den < 0.f) ? -1e-5f : 1e-5f;
    wrow[32 + (tid-16)] = 1.0f/den;
  }

  for (int k0=0; k0<NN; k0+=16){
    __syncthreads();   // prev chunk's frag reads done; this chunk's wrow published
    const int buf = (k0>>4)&1;
    const float* wA = wrow + buf*16;
    const float* wB = wrow + 32 + buf*16;
    // stage: items = (kg 0..1) x (col 0..D-1); lane-consecutive cols
    for (int it = tid; it < 2*D; it += BLK){
      const int kg  = it / D;
      const int col = it - kg*D;
      const u16x8 xh8 = XPH[(size_t)((k0>>3)+kg)*D + col];
      const u16x8 xl8 = XPL[(size_t)((k0>>3)+kg)*D + col];
      const float4 wa0 = *reinterpret_cast<const float4*>(&wA[kg*8]);
      const float4 wa1 = *reinterpret_cast<const float4*>(&wA[kg*8+4]);
      const float4 wb0 = *reinterpret_cast<const float4*>(&wB[kg*8]);
      const float4 wb1 = *reinterpret_cast<const float4*>(&wB[kg*8+4]);
      const float wva[8] = {wa0.x,wa0.y,wa0.z,wa0.w,wa1.x,wa1.y,wa1.z,wa1.w};
      const float wvb[8] = {wb0.x,wb0.y,wb0.z,wb0.w,wb1.x,wb1.y,wb1.z,wb1.w};
      u16x8 sphA, splA, sphB, splB;
#pragma unroll
      for (int j=0;j<8;j++){
        const float hf = __uint_as_float((uint32_t)(uint16_t)xh8[j]<<16);
        const float lf = __uint_as_float((uint32_t)(uint16_t)xl8[j]<<16);
        const float xt = hf + lf;
        const float pA = wva[j]*xt;
        const uint16_t hA = bf16hi(pA);
        sphA[j] = hA;
        splA[j] = bf16hi(pA - __uint_as_float((uint32_t)hA<<16));
        const float pB = wvb[j]*xt;
        const uint16_t hB = bf16hi(pB);
        sphB[j] = hB;
        splB[j] = bf16hi(pB - __uint_as_float((uint32_t)hB<<16));
      }
      const int base = col*SXT + kg*8;
      *reinterpret_cast<u16x8*>(XTh + base) = xh8;
      *reinterpret_cast<u16x8*>(XTl + base) = xl8;
      *reinterpret_cast<u16x8*>(WAh + base) = sphA;
      *reinterpret_cast<u16x8*>(WAl + base) = splA;
      *reinterpret_cast<u16x8*>(WBh + base) = sphB;
      *reinterpret_cast<u16x8*>(WBl + base) = splB;
    }
    // next chunk's pole weights into the other buffer
    if (k0+16 < NN){
      if (tid < 16){
        float den = a[k0+16+tid] - tA;
        if (fabsf(den) < 1e-5f) den = (den < 0.f) ? -1e-5f : 1e-5f;
        wrow[((buf^1)<<4) + tid] = 1.0f/den;
      } else if (tid < 32){
        float den = a[k0+16+(tid-16)] - tB;
        if (fabsf(den) < 1e-5f) den = (den < 0.f) ? -1e-5f : 1e-5f;
        wrow[32 + ((buf^1)<<4) + (tid-16)] = 1.0f/den;
      }
    }
    __syncthreads();   // XT/W arrays + next wrow ready
    const s16x8 aAh0 = *reinterpret_cast<const s16x8*>(WAh + colA*SXT + kgo);
    const s16x8 aAh1 = *reinterpret_cast<const s16x8*>(WAh + (colA+32)*SXT + kgo);
    const s16x8 aAl0 = *reinterpret_cast<const s16x8*>(WAl + colA*SXT + kgo);
    const s16x8 aAl1 = *reinterpret_cast<const s16x8*>(WAl + (colA+32)*SXT + kgo);
    const s16x8 aBh0 = *reinterpret_cast<const s16x8*>(WBh + colA*SXT + kgo);
    const s16x8 aBh1 = *reinterpret_cast<const s16x8*>(WBh + (colA+32)*SXT + kgo);
    const s16x8 aBl0 = *reinterpret_cast<const s16x8*>(WBl + colA*SXT + kgo);
    const s16x8 aBl1 = *reinterpret_cast<const s16x8*>(WBl + (colA+32)*SXT + kgo);
    const s16x8 bh0 = *reinterpret_cast<const s16x8*>(XTh + colB*SXT + kgo);
    const s16x8 bh1 = *reinterpret_cast<const s16x8*>(XTh + (colB+32)*SXT + kgo);
    const s16x8 bl0 = *reinterpret_cast<const s16x8*>(XTl + colB*SXT + kgo);
    const s16x8 bl1 = *reinterpret_cast<const s16x8*>(XTl + (colB+32)*SXT + kgo);
    // 24 MFMAs, 8 independent chains; per-chain order matches single-t version
    accA0 = __builtin_amdgcn_mfma_f32_32x32x16_bf16(aAh0, bh0, accA0, 0,0,0);
    accB0 = __builtin_amdgcn_mfma_f32_32x32x16_bf16(aBh0, bh0, accB0, 0,0,0);
    accA1 = __builtin_amdgcn_mfma_f32_32x32x16_bf16(aAh0, bh1, accA1, 0,0,0);
    accB1 = __builtin_amdgcn_mfma_f32_32x32x16_bf16(aBh0, bh1, accB1, 0,0,0);
    accA2 = __builtin_amdgcn_mfma_f32_32x32x16_bf16(aAh1, bh0, accA2, 0,0,0);
    accB2 = __builtin_amdgcn_mfma_f32_32x32x16_bf16(aBh1, bh0, accB2, 0,0,0);
    accA3 = __builtin_amdgcn_mfma_f32_32x32x16_bf16(aAh1, bh1, accA3, 0,0,0);
    accB3 = __builtin_amdgcn_mfma_f32_32x32x16_bf16(aBh1, bh1, accB3, 0,0,0);
    accA0 = __builtin_amdgcn_mfma_f32_32x32x16_bf16(aAh0, bl0, accA0, 0,0,0);
    accB0 = __builtin_amdgcn_mfma_f32_32x32x16_bf16(aBh0, bl0, accB0, 0,0,0);
    accA1 = __builtin_amdgcn_mfma_f32_32x32x16_bf16(aAh0, bl1, accA1, 0,0,0);
    accB1 = __builtin_amdgcn_mfma_f32_32x32x16_bf16(aBh0, bl1, accB1, 0,0,0);
    accA2 = __builtin_amdgcn_mfma_f32_32x32x16_bf16(aAh1, bl0, accA2, 0,0,0);
    accB2 = __builtin_amdgcn_mfma_f32_32x32x16_bf16(aBh1, bl0, accB2, 0,0,0);
    accA3 = __builtin_amdgcn_mfma_f32_32x32x16_bf16(aAh1, bl1, accA3, 0,0,0);
    accB3 = __builtin_amdgcn_mfma_f32_32x32x16_bf16(aBh1, bl1, accB3, 0,0,0);
    accA0 = __builtin_amdgcn_mfma_f32_32x32x16_bf16(aAl0, bh0, accA0, 0,0,0);
    accB0 = __builtin_amdgcn_mfma_f32_32x32x16_bf16(aBl0, bh0, accB0, 0,0,0);
    accA1 = __builtin_amdgcn_mfma_f32_32x32x16_bf16(aAl0, bh1, accA1, 0,0,0);
    accB1 = __builtin_amdgcn_mfma_f32_32x32x16_bf16(aBl0, bh1, accB1, 0,0,0);
    accA2 = __builtin_amdgcn_mfma_f32_32x32x16_bf16(aAl1, bh0, accA2, 0,0,0);
    accB2 = __builtin_amdgcn_mfma_f32_32x32x16_bf16(aBl1, bh0, accB2, 0,0,0);
    accA3 = __builtin_amdgcn_mfma_f32_32x32x16_bf16(aAl1, bh1, accA3, 0,0,0);
    accB3 = __builtin_amdgcn_mfma_f32_32x32x16_bf16(aBl1, bh1, accB3, 0,0,0);
  }
  __syncthreads();   // last frag reads done before M overwrite

  // ---- phase 2b writer: M = I - G (packed upper triangle, row-major) ----
  auto writeM = [&](const f32x16& A0, const f32x16& A1, const f32x16& A2, const f32x16& A3){
    const int rbase = 4*(lane>>5);
#pragma unroll
    for (int q=0;q<4;q++){
      const f32x16& A = (q==0)?A0:((q==1)?A1:((q==2)?A2:A3));
      const int ta = 2*bi + (q>>1), tb = 2*bj + (q&1);
      const int bb = tb*32 + (lane & 31);
#pragma unroll
      for (int r=0;r<16;r++){
        const int aa = ta*32 + (r&3) + 8*(r>>2) + rbase;
        if (aa <= bb)
          M[aa*D - (aa*(aa-1))/2 + (bb-aa)] = ((aa==bb)?1.f:0.f) - A[r];
      }
    }
  };

  // ---- phase 3: panel-8 blocked LDL^T (neg valid on tid 0) ----
  constexpr int PS = 12;   // Pt stride: 48B -> 16B-aligned, bank-spread
  auto ldlt = [&]()->int{
    int neg = 0;
    for (int kp=0; kp<D; kp+=8){
      const int k1 = kp+8;
      __syncthreads();    // prev trailing / phase-2b visible
      if (tid < 64){
        if (tid == 0){
          float B[8][8];
#pragma unroll
          for (int q=0;q<8;q++){
#pragma unroll
            for (int p=0;p<=q;p++){
              const int g = kp+p;
              B[p][q] = M[g*D - (g*(g-1))/2 + (kp+q-g)];
            }
          }
          float inv8[8];
#pragma unroll
          for (int q=0;q<8;q++){
            float d = B[q][q];
            if (d < 0.f) neg++;
            if (fabsf(d) < 1e-8f) d = (d<0.f)?-1e-8f:1e-8f;
            const float inv = 1.0f/d;
            inv8[q] = inv;
#pragma unroll
            for (int i=q+1;i<8;i++){
              const float f = B[q][i]*inv;
#pragma unroll
              for (int j=i;j<8;j++) B[i][j] = fmaf(-f, B[q][j], B[i][j]);
            }
          }
#pragma unroll
          for (int q=0;q<8;q++){
            fsc[36+q] = inv8[q];
#pragma unroll
            for (int p=0;p<=q;p++) fsc[(q*(q+1))/2 + p] = B[p][q];
          }
        }
        __asm__ __volatile__("s_waitcnt lgkmcnt(0)" ::: "memory");  // wave-sync publish
        float c8[36], iv8[8];
#pragma unroll
        for (int k=0;k<36;k++) c8[k] = fsc[k];
#pragma unroll
        for (int k=0;k<8;k++) iv8[k] = fsc[36+k];
        for (int j = k1 + tid; j < D; j += 64){
          float rv[8], pt[8];
#pragma unroll
          for (int q=0;q<8;q++){
            const int g = kp+q;
            rv[q] = M[g*D - (g*(g-1))/2 + (j-g)];
          }
#pragma unroll
          for (int q=0;q<8;q++){
            float v = rv[q];
#pragma unroll
            for (int p=0;p<q;p++) v = fmaf(-c8[(q*(q+1))/2 + p], pt[p], v);
            pt[q] = v * iv8[q];
            const int g = kp+q;
            M[g*D - (g*(g-1))/2 + (j-g)] = v;
            Pt[j*PS + q] = pt[q];
          }
        }
      }
      __syncthreads();    // publish panel rows + Pt
      if (k1 < D){
        constexpr int G = BLK/4;
        const int grp = tid / G, sub = tid % G;
        for (int i0=k1; i0<D; i0+=4){
          const int i = i0 + grp;
          float cq[8];
#pragma unroll
          for (int q=0;q<8;q++){
            const int g = kp+q;
            cq[q] = M[g*D - (g*(g-1))/2 + (i-g)];
          }
          const int offi = i*D - (i*(i-1))/2;
          for (int j=i+sub; j<D; j+=G){
            const float4 p0 = *reinterpret_cast<const float4*>(&Pt[j*PS + 0]);
            const float4 p1 = *reinterpret_cast<const float4*>(&Pt[j*PS + 4]);
            float v = M[offi + (j-i)];
            v = fmaf(-cq[0],p0.x,v); v = fmaf(-cq[1],p0.y,v);
            v = fmaf(-cq[2],p0.z,v); v = fmaf(-cq[3],p0.w,v);
            v = fmaf(-cq[4],p1.x,v); v = fmaf(-cq[5],p1.y,v);
            v = fmaf(-cq[6],p1.z,v); v = fmaf(-cq[7],p1.w,v);
            M[offi + (j-i)] = v;
          }
        }
      }
    }
    return neg;
  };

  // t0: build M, factor, count
  writeM(accA0, accA1, accA2, accA3);
  const int negA = ldlt();
  if (tid == 0) ((int*)scal)[5] = negA;
  __syncthreads();   // phase-3(t0) fully done; negA published
  // t1: rebuild M from registers, factor, count
  writeM(accB0, accB1, accB2, accB3);
  const int negB = ldlt();
  if (tid == 0) ((int*)scal)[6] = negB;
  __syncthreads();
  const int nA = ((int*)scal)[5];
  const int nB = ((int*)scal)[6];
  __syncthreads();

  *tOutA = tA; *tOutB = tB;
  *nuOutA = nA + (int)(cntA + 0.5f);
  *nuOutB = nB + (int)(cntB + 0.5f);
}

#define SMEM_D(D) (((D)*((D)+1)/2 + 12*(D) + 160)*4)

// coarse grid eval: each block evaluates bins b0=2k and b0+1
template<int D, int BLK, int WPE>
__global__ __launch_bounds__(BLK,WPE) void k_eval(const uint16_t* __restrict__ xph,
    const uint16_t* __restrict__ xpl,
    const float* __restrict__ ab, const float* __restrict__ ctrlF,
    const int* __restrict__ ctrlI, int* __restrict__ nu1, float* __restrict__ tus1)
{
  const int dim = blockIdx.y;
  const int b0 = blockIdx.x*2, b1 = b0+1;
  if (b0 > ctrlI[dim*8+0]) return;
  extern __shared__ float smem[];
  constexpr int TRI = D*(D+1)/2;
  float* M = smem; float* Pt = M+TRI; float* red = Pt + 12*D;
  float* wrow = red+32; float* scal = wrow+64;
  const float lo = ctrlF[dim*8+0], h1 = ctrlF[dim*8+1];
  float tUA, tUB; int vA, vB;
  evalNu2<D,BLK>(xph + (size_t)dim*NN*D, xpl + (size_t)dim*NN*D,
                 ab + dim*NN, lo + h1*b0, lo + h1*b1, NUDGE,
                 M,Pt,red,wrow,scal,&tUA,&tUB,&vA,&vB);
  if (threadIdx.x == 0){
    nu1[dim*(MAXB1+1)+b0] = vA; tus1[dim*(MAXB1+1)+b0] = tUA;
    if (b1 <= MAXB1){ nu1[dim*(MAXB1+1)+b1] = vB; tus1[dim*(MAXB1+1)+b1] = tUB; }
  }
}

// fine eval: 7 interior points per bin, paired (s0,s0+1) -> 4 blocks/task
template<int D, int BLK, int WPE>
__global__ __launch_bounds__(BLK,WPE) void k_evalF(const uint16_t* __restrict__ xph,
    const uint16_t* __restrict__ xpl,
    const float* __restrict__ ab, const float* __restrict__ ctrlF,
    const int* __restrict__ ctrlI, const int* __restrict__ fineBins,
    int* __restrict__ nuF, float* __restrict__ tusF)
{
  const int dim = blockIdx.y;
  const int task = blockIdx.x >> 2;
  int cnt = ctrlI[dim*8+3]; if (cnt > NFMAX) cnt = NFMAX;
  if (task >= cnt) return;
  const int r = blockIdx.x & 3;
  const int s0 = 2*r + 1, s1 = s0 + 1;     // s1==8 invalid (not stored)
  const int bin = fineBins[dim*NFMAX + task];
  extern __shared__ float smem[];
  constexpr int TRI = D*(D+1)/2;
  float* M = smem; float* Pt = M+TRI; float* red = Pt + 12*D;
  float* wrow = red+32; float* scal = wrow+64;
  const float lo = ctrlF[dim*8+0], hf = ctrlF[dim*8+1]*(1.0f/SUBD);
  const int f0 = bin*SUBD + s0, f1 = bin*SUBD + s1;
  float tUA, tUB; int vA, vB;
  evalNu2<D,BLK>(xph + (size_t)dim*NN*D, xpl + (size_t)dim*NN*D,
                 ab + dim*NN, lo + hf*f0, lo + hf*f1, NUDGE,
                 M,Pt,red,wrow,scal,&tUA,&tUB,&vA,&vB);
  if (threadIdx.x == 0){
    nuF[(size_t)dim*NBF+f0] = vA; tusF[(size_t)dim*NBF+f0] = tUA;
    if (s1 < SUBD){ nuF[(size_t)dim*NBF+f1] = vB; tusF[(size_t)dim*NBF+f1] = tUB; }
  }
}

// one-shot probes: NPB points per side, paired (2*ip, 2*ip+1) -> 4 blocks/run
template<int D, int BLK, int WPE>
__global__ __launch_bounds__(BLK,WPE) void k_probe(const uint16_t* __restrict__ xph,
    const uint16_t* __restrict__ xpl,
    const float* __restrict__ ab, const int* __restrict__ ctrlI,
    const int* __restrict__ runP, const float* __restrict__ runB,
    int* __restrict__ nuP, float* __restrict__ tP)
{
  const int dim = blockIdx.y;
  const int r = blockIdx.x >> 2;
  int nr = ctrlI[dim*8+1]; if (nr > MAXRUN) nr = MAXRUN;
  if (r >= nr) return;
  const int side = (blockIdx.x >> 1) & 1;
  const int ip = blockIdx.x & 1;
  const int i0 = 2*ip, i1 = i0+1;
  extern __shared__ float smem[];
  constexpr int TRI = D*(D+1)/2;
  float* M = smem; float* Pt = M+TRI; float* red = Pt + 12*D;
  float* wrow = red+32; float* scal = wrow+64;
  const float* rb = runB + (size_t)(dim*MAXRUN + r)*4;
  const float lo = rb[side*2+0], hi = rb[side*2+1];
  const float t0 = lo + (hi - lo)*(float)(i0+1)*(1.0f/(NPB+1));
  const float t1 = lo + (hi - lo)*(float)(i1+1)*(1.0f/(NPB+1));
  const float dlt = fminf(NUDGE, (hi-lo)*0.08f);
  float tUA, tUB; int vA, vB;
  evalNu2<D,BLK>(xph + (size_t)dim*NN*D, xpl + (size_t)dim*NN*D,
                 ab + dim*NN, t0, t1, dlt,
                 M,Pt,red,wrow,scal,&tUA,&tUB,&vA,&vB);
  if (threadIdx.x == 0){
    const size_t o = (((size_t)dim*MAXRUN + r)*2 + side)*NPB;
    nuP[o+i0] = vA; tP[o+i0] = tUA;
    nuP[o+i1] = vB; tP[o+i1] = tUB;
  }
}

__global__ void k_decide(const int* __restrict__ ctrlI, const int* __restrict__ runP,
                         const float* __restrict__ runB, const int* __restrict__ nuP,
                         const float* __restrict__ tP, int* __restrict__ bnd){
  const int dim = blockIdx.x;
  int nr = ctrlI[dim*8+1]; if (nr > MAXRUN) nr = MAXRUN;
  for (int r = threadIdx.x; r < nr; r += blockDim.x){
    const int p = runP[dim*MAXRUN + r];
    const float* rb = runB + (size_t)(dim*MAXRUN + r)*4;
    float lam[2];
    for (int side=0; side<2; side++){
      const int rank = p + side;   // nu(t) >= rank  <=>  lam_rank < t
      const size_t o = (((size_t)dim*MAXRUN + r)*2 + side)*NPB;
      float prev = rb[side*2+0];
      bool found = false; float l = 0.f;
      for (int i=0;i<NPB;i++){
        const float ti = tP[o+i];
        if (nuP[o+i] >= rank){ l = 0.5f*(prev + ti); found = true; break; }
        prev = ti;
      }
      if (!found) l = 0.5f*(prev + rb[side*2+1]);
      lam[side] = l;
    }
    if (lam[1] - lam[0] > THRG) bnd[dim*NN + p - 1] = 1;
  }
}

// select nonempty coarse bins for subdivision (parallel, atomic append)
__global__ void k_sel(const int* __restrict__ nu1, int* ctrlI,
                      int* __restrict__ binSel, int* __restrict__ fineBins){
  const int dim = blockIdx.y;
  const int j = blockIdx.x*256 + threadIdx.x;
  const int nb1 = ctrlI[dim*8+0];
  if (j >= nb1) return;
  const int* nv = nu1 + dim*(MAXB1+1);
  if (nv[j+1] != nv[j]){
    const int slot = atomicAdd(&ctrlI[dim*8+3], 1);
    if (slot < NFMAX){ binSel[dim*MAXB1+j] = slot; fineBins[dim*NFMAX+slot] = j; }
    else binSel[dim*MAXB1+j] = -2;
  } else binSel[dim*MAXB1+j] = -1;
}

// fill combined fine-resolution arrays (fine eval overwrites its slots after)
__global__ void k_fill(const int* __restrict__ nu1, const float* __restrict__ tus1,
                       const int* __restrict__ binSel, const float* __restrict__ ctrlF,
                       const int* __restrict__ ctrlI,
                       int* __restrict__ nuF, float* __restrict__ tusF){
  const int dim = blockIdx.y;
  const int f = blockIdx.x*256 + threadIdx.x;
  const int nb1 = ctrlI[dim*8+0];
  if (f > nb1*SUBD) return;
  const int j = f / SUBD, s = f % SUBD;
  const float lo = ctrlF[dim*8+0], hf = ctrlF[dim*8+1]*(1.0f/SUBD);
  int v; float tv;
  if (s == 0){ v = nu1[dim*(MAXB1+1)+j]; tv = tus1[dim*(MAXB1+1)+j]; }
  else {
    const int sel = binSel[dim*MAXB1+j];
    tv = lo + hf*f;
    if (sel == -2) v = 0x40000000 + f;       // sentinel: suppress runs here
    else v = nu1[dim*(MAXB1+1)+j];           // empty bin: exact by monotonicity
  }
  nuF[(size_t)dim*NBF+f] = v;
  tusF[(size_t)dim*NBF+f] = tv;
}

// parallel run detection on the merged fine array.
// Span early-exit: tu monotone => once scanned span > THRG the final gmin
// must exceed THRG too -> decide bnd=1 without finding the true run end.
__global__ void k_runs(const int* __restrict__ nuF, const float* __restrict__ tusF,
                       int* ctrlI, int* __restrict__ runP, float* __restrict__ runB,
                       int* __restrict__ bnd){
  const int dim = blockIdx.y;
  const int b1 = blockIdx.x*256 + threadIdx.x;
  const int nbt = ctrlI[dim*8+0]*SUBD;
  if (b1 >= nbt) return;
  const int* nv = nuF + (size_t)dim*NBF;
  const float* tu = tusF + (size_t)dim*NBF;
  if (nv[b1+1] != nv[b1]) return;              // not an empty bin
  if (b1 > 0 && nv[b1-1] == nv[b1]) return;    // not the run start
  const int p = nv[b1];
  if (p < 1 || p > NN-1 || b1 < 1) return;     // reject BEFORE the scan
  const float tb1 = tu[b1];
  int j2 = b1;
  while (j2+1 < nbt && nv[j2+2] == nv[j2+1]){
    j2++;
    if (tu[j2+1] - tb1 > THRG){ bnd[dim*NN + p-1] = 1; return; }
  }
  if (j2 > nbt-2) return;
  const float gmin = tu[j2+1] - tb1;
  const float gmax = tu[j2+2] - tu[b1-1];
  if (gmin > THRG){ bnd[dim*NN + p-1] = 1; return; }
  if (gmax > THRG){
    const int slot = atomicAdd(&ctrlI[dim*8+1], 1);
    if (slot < MAXRUN){
      runP[dim*MAXRUN + slot] = p;
      float* rb = runB + (size_t)(dim*MAXRUN + slot)*4;
      rb[0]=tu[b1-1]; rb[1]=tu[b1]; rb[2]=tu[j2+1]; rb[3]=tu[j2+2];
    }
  }
}

// ============================ power iteration (multi-launch) ============
__global__ void k_pw_init(float* __restrict__ vG, float* __restrict__ scACC){
  const int dim = blockIdx.x, tid = threadIdx.x;
  float* v = vG + (size_t)dim*NN;
  for (int i=tid;i<NN;i+=1024){
    uint32_t hsh = (uint32_t)i*2654435761u;
    v[i] = 1.0f + 2e-4f*(float)(hsh>>20);
  }
  if (tid == 0){ scACC[0*ND*2 + dim*2 + 0] = 1.0f; scACC[0*ND*2 + dim*2 + 1] = 0.f; }
}

template<int D>
__global__ __launch_bounds__(D) void k_pw_z(const float* __restrict__ xnb,
    const float* __restrict__ vG, float* __restrict__ zpart,
    float* __restrict__ scACC, int parReset){
  const int dim = blockIdx.y, seg = blockIdx.x, c = threadIdx.x;
  const float* x = xnb + (size_t)dim*NN*D;
  const float* v = vG + (size_t)dim*NN;
  const int i0 = seg*(NN/16);
  float acc = 0.f;
  for (int r=0;r<NN/16;r++){
    const int i = i0 + r;
    acc = fmaf(x[(size_t)i*D + c], v[i], acc);
  }
  zpart[((size_t)dim*16 + seg)*DMX + c] = acc;
  if (seg == 0 && c < 2) scACC[parReset*ND*2 + dim*2 + c] = 0.f;
}

template<int D>
__global__ __launch_bounds__(256) void k_pw_y(const float* __restrict__ xnb,
    const float* __restrict__ ab, const uint32_t* __restrict__ ctrlU,
    const float* __restrict__ zpart, float* __restrict__ vG,
    float* __restrict__ scACC, int parPrev, int parCur){
  constexpr int VEC = D/64;
  const int dim = blockIdx.y, seg = blockIdx.x, tid = threadIdx.x;
  const int w = tid >> 6, lane = tid & 63;
  const float* x = xnb + (size_t)dim*NN*D;
  const float* a = ab + dim*NN;
  float* v = vG + (size_t)dim*NN;
  __shared__ float zs[DMX];
  __shared__ float redn[4], redr[4];
  if (tid < D){
    float s = 0.f;
#pragma unroll
    for (int k=0;k<16;k++) s += zpart[((size_t)dim*16 + k)*DMX + tid];
    zs[tid] = s;
  }
  __syncthreads();
  const float amax = decF(ctrlU[dim*8+1]);
  const float invPrev = rsqrtf(fmaxf(scACC[parPrev*ND*2 + dim*2 + 0], 1e-30f));
  float zr[VEC];
#pragma unroll
  for (int k=0;k<VEC;k++) zr[k] = zs[lane*VEC + k];
  float n2 = 0.f, ray = 0.f;
  for (int r=0;r<32;r++){
    const int i = seg*(NN/16) + w*32 + r;
    const float* xr = x + (size_t)i*D + lane*VEC;
    float dot = 0.f;
#pragma unroll
    for (int k=0;k<VEC;k++) dot = fmaf(xr[k], zr[k], dot);
#pragma unroll
    for (int o=32;o>0;o>>=1) dot += __shfl_xor(dot,o,64);
    if (lane == 0){
      const float vr = v[i];
      const float y = invPrev * fmaf(amax - a[i], vr, dot);
      n2 = fmaf(y,y,n2); ray = fmaf(vr*invPrev, y, ray);
      v[i] = y;
    }
  }
  if (lane == 0){ redn[w] = n2; redr[w] = ray; }
  __syncthreads();
  if (tid == 0){
    float sn = redn[0]+redn[1]+redn[2]+redn[3];
    float sr = redr[0]+redr[1]+redr[2]+redr[3];
    atomicAdd(&scACC[parCur*ND*2 + dim*2 + 0], sn);
    atomicAdd(&scACC[parCur*ND*2 + dim*2 + 1], sr);
  }
}

__global__ void k_pw_fin(const float* __restrict__ scACC, float* __restrict__ thB,
                         int slot){
  if (threadIdx.x < ND) thB[threadIdx.x] = scACC[slot*ND*2 + threadIdx.x*2 + 1];
}

// ============================ graph / GCN kernels ============================
__global__ void k_init(float* deg, int* cur){
  const int dim = blockIdx.x;
  for (int i=threadIdx.x;i<NN;i+=blockDim.x){ deg[dim*NN+i] = 1.0f; cur[dim*NN+i] = 0; }
}
__global__ void k_count(const int* __restrict__ eidx, const float* __restrict__ ew,
                        float* deg, int* cur){
  const int idx = blockIdx.x*256 + threadIdx.x;
  if (idx >= ND*NE) return;
  const int dim = idx / NE, e = idx % NE;
  const int dst = eidx[(size_t)dim*2*NE + NE + e];
  atomicAdd(&cur[dim*NN + dst], 1);
  atomicAdd(&deg[dim*NN + dst], ew[(size_t)dim*NE + e]);
}
__global__ void k_prefix(int* cur, int* base){
  const int dim = blockIdx.x;
  if (threadIdx.x) return;
  int* b = base + dim*(NN+1);
  int* cc = cur + dim*NN;
  int run = 0; b[0] = 0;
  for (int i=0;i<NN;i++){ int cnt = cc[i]; cc[i] = run; b[i+1] = run + cnt; run += cnt; }
}
__global__ void k_fill_csr(const int* __restrict__ eidx, const float* __restrict__ ew,
                       const float* __restrict__ deg, int* cur, int* psrc, float* coef){
  const int idx = blockIdx.x*256 + threadIdx.x;
  if (idx >= ND*NE) return;
  const int dim = idx / NE, e = idx % NE;
  const int src = eidx[(size_t)dim*2*NE + e];
  const int dst = eidx[(size_t)dim*2*NE + NE + e];
  const int slot = atomicAdd(&cur[dim*NN + dst], 1);
  psrc[(size_t)dim*NE + slot] = src;
  const float ds = deg[dim*NN + src], dd = deg[dim*NN + dst];
  coef[(size_t)dim*NE + slot] = ew[(size_t)dim*NE + e] * (1.0f/sqrtf(ds)) * (1.0f/sqrtf(dd));
}
__global__ void k_selfw(const float* deg, float* sw){
  const int idx = blockIdx.x*256 + threadIdx.x;
  if (idx < ND*NN) sw[idx] = 1.0f/deg[idx];
}

// generic tiled GEMM: C[M,P] = A[M,K] @ W[K,P] (+bias). grid z = dim axis.
__global__ __launch_bounds__(256) void k_gemm(const float* __restrict__ A, long long aStr,
    const float* __restrict__ W, long long wStr,
    const float* __restrict__ bias, long long bStr,
    float* __restrict__ C, long long cStr, int M, int K, int P)
{
  const int dim = blockIdx.z;
  A += (size_t)dim*aStr; W += (size_t)dim*wStr; C += (size_t)dim*cStr;
  if (bias) bias += (size_t)dim*bStr;
  __shared__ float As[64][17];
  __shared__ float Bs[16][68];
  const int tid = threadIdx.x;
  const int tx = tid % 16, ty = tid / 16;
  const int m0 = blockIdx.y*64, p0 = blockIdx.x*64;
  float acc[4][4] = {};
  for (int k0=0;k0<K;k0+=16){
    __syncthreads();
    { int r = tid/4, c4 = (tid%4)*4;
      float4 v = *reinterpret_cast<const float4*>(A + (size_t)(m0+r)*K + k0 + c4);
      As[r][c4]=v.x; As[r][c4+1]=v.y; As[r][c4+2]=v.z; As[r][c4+3]=v.w; }
    { int r = tid/16, c4 = (tid%16)*4;
      float4 v = *reinterpret_cast<const float4*>(W + (size_t)(k0+r)*P + p0 + c4);
      Bs[r][c4]=v.x; Bs[r][c4+1]=v.y; Bs[r][c4+2]=v.z; Bs[r][c4+3]=v.w; }
    __syncthreads();
#pragma unroll
    for (int kk=0;kk<16;kk++){
      float a0=As[ty*4+0][kk], a1=As[ty*4+1][kk], a2=As[ty*4+2][kk], a3=As[ty*4+3][kk];
      float b0=Bs[kk][tx*4+0], b1=Bs[kk][tx*4+1], b2=Bs[kk][tx*4+2], b3=Bs[kk][tx*4+3];
      acc[0][0]=fmaf(a0,b0,acc[0][0]); acc[0][1]=fmaf(a0,b1,acc[0][1]);
      acc[0][2]=fmaf(a0,b2,acc[0][2]); acc[0][3]=fmaf(a0,b3,acc[0][3]);
      acc[1][0]=fmaf(a1,b0,acc[1][0]); acc[1][1]=fmaf(a1,b1,acc[1][1]);
      acc[1][2]=fmaf(a1,b2,acc[1][2]); acc[1][3]=fmaf(a1,b3,acc[1][3]);
      acc[2][0]=fmaf(a2,b0,acc[2][0]); acc[2][1]=fmaf(a2,b1,acc[2][1]);
      acc[2][2]=fmaf(a2,b2,acc[2][2]); acc[2][3]=fmaf(a2,b3,acc[2][3]);
      acc[3][0]=fmaf(a3,b0,acc[3][0]); acc[3][1]=fmaf(a3,b1,acc[3][1]);
      acc[3][2]=fmaf(a3,b2,acc[3][2]); acc[3][3]=fmaf(a3,b3,acc[3][3]);
    }
  }
  for (int i=0;i<4;i++){
    for (int j=0;j<4;j++){
      const int pp = p0 + tx*4 + j;
      float v = acc[i][j];
      if (bias) v += bias[pp];
      C[(size_t)(m0+ty*4+i)*P + pp] = v;
    }
  }
}

__global__ void k_agg(const float* __restrict__ h, float* __restrict__ g,
                      const float* __restrict__ convb, const int* __restrict__ base,
                      const int* __restrict__ psrc, const float* __restrict__ coef,
                      const float* __restrict__ selfw, int co)
{
  const int i = blockIdx.x, dim = blockIdx.y, c = threadIdx.x;
  const float* hD = h + (size_t)dim*NN*co;
  const int s = base[dim*(NN+1)+i], e = base[dim*(NN+1)+i+1];
  const int* ps = psrc + (size_t)dim*NE;
  const float* cf = coef + (size_t)dim*NE;
  float acc = 0.f;
  for (int q=s;q<e;q++) acc += cf[q]*hD[(size_t)ps[q]*co + c];
  g[((size_t)dim*NN+i)*co + c] = acc + hD[(size_t)i*co + c]*selfw[dim*NN+i] + convb[dim*co + c];
}

__global__ void k_rownorm(const float* __restrict__ g, float* __restrict__ xn, int co){
  const int i = blockIdx.x, dim = blockIdx.y;
  const float* gr = g + ((size_t)dim*NN+i)*co;
  float* xr = xn + ((size_t)dim*NN+i)*co;
  float p = 0.f;
  for (int c=threadIdx.x;c<co;c+=256){ float v = gr[c]; p += v*v; }
  __shared__ float red[4];
  p = wredSum(p);
  if ((threadIdx.x&63)==0) red[threadIdx.x>>6] = p;
  __syncthreads();
  if (threadIdx.x==0) red[0] = red[0]+red[1]+red[2]+red[3];
  __syncthreads();
  const float inv = 1.0f/(sqrtf(red[0]) + 1e-8f);
  for (int c=threadIdx.x;c<co;c+=256) xr[c] = gr[c]*inv;
}

// 256 threads: 4-way row-split partial sums + LDS reduce
__global__ void k_colsum(const float* __restrict__ xn, float* __restrict__ sb, int co){
  const int lane = threadIdx.x & 63;
  const int seg  = threadIdx.x >> 6;           // 0..3
  const int c = blockIdx.x*64 + lane;
  const int dim = blockIdx.y;
  const float* x = xn + (size_t)dim*NN*co;
  float s = 0.f;
  for (int i=seg*(NN/4); i<(seg+1)*(NN/4); i++) s += x[(size_t)i*co + c];
  __shared__ float part[4][64];
  part[seg][lane] = s;
  __syncthreads();
  if (threadIdx.x < 64)
    sb[dim*DMX + c] = part[0][lane]+part[1][lane]+part[2][lane]+part[3][lane];
}

// wave-per-row; 8 rows/block; one atomic pair per block
__global__ __launch_bounds__(512) void k_adot(const float* __restrict__ xn,
                       const float* __restrict__ sb,
                       float* __restrict__ ab, uint32_t* ctrlU, int co){
  const int dim = blockIdx.y;
  const int w = threadIdx.x >> 6, lane = threadIdx.x & 63;
  const int i = blockIdx.x*8 + w;
  const float* x = xn + ((size_t)dim*NN + i)*co;
  const float* s = sb + dim*DMX;
  float p = 0.f;
  for (int c=lane;c<co;c+=64) p = fmaf(x[c], s[c], p);
  p = wredSum(p);
  __shared__ uint32_t rmn[8], rmx[8];
  if (lane==0){
    ab[dim*NN+i] = p;
    const uint32_t e = encF(p);
    rmn[w] = e; rmx[w] = e;
  }
  __syncthreads();
  if (threadIdx.x==0){
    uint32_t mn = rmn[0], mx = rmx[0];
#pragma unroll
    for (int k=1;k<8;k++){
      mn = (rmn[k] < mn) ? rmn[k] : mn;
      mx = (rmx[k] > mx) ? rmx[k] : mx;
    }
    atomicMin(&ctrlU[dim*8+0], mn);
    atomicMax(&ctrlU[dim*8+1], mx);
  }
}

__global__ __launch_bounds__(256) void k_gramC(const float* __restrict__ xn,
                                               float* __restrict__ Cb, int co){
  const int dim = blockIdx.y;
  const int nbx = co/32;
  const int bx = blockIdx.x % nbx, by = blockIdx.x / nbx;
  const float* x = xn + (size_t)dim*NN*co;
  float* C = Cb + (size_t)dim*co*co;
  __shared__ float Xa[64][33];
  __shared__ float Xb[64][33];
  const int tid = threadIdx.x;
  const int ty = tid/16, tx = tid%16;
  float a00=0,a01=0,a10=0,a11=0;
  for (int i0=0;i0<NN;i0+=64){
    __syncthreads();
    for (int l=tid;l<512;l+=256){
      const int r = l/8, c4 = (l%8)*4;
      float4 va = *reinterpret_cast<const float4*>(x + (size_t)(i0+r)*co + by*32 + c4);
      Xa[r][c4]=va.x; Xa[r][c4+1]=va.y; Xa[r][c4+2]=va.z; Xa[r][c4+3]=va.w;
      float4 vb = *reinterpret_cast<const float4*>(x + (size_t)(i0+r)*co + bx*32 + c4);
      Xb[r][c4]=vb.x; Xb[r][c4+1]=vb.y; Xb[r][c4+2]=vb.z; Xb[r][c4+3]=vb.w;
    }
    __syncthreads();
#pragma unroll 8
    for (int r=0;r<64;r++){
      const float u0=Xa[r][ty*2], u1=Xa[r][ty*2+1], w0=Xb[r][tx*2], w1=Xb[r][tx*2+1];
      a00=fmaf(u0,w0,a00); a01=fmaf(u0,w1,a01); a10=fmaf(u1,w0,a10); a11=fmaf(u1,w1,a11);
    }
  }
  const int ca = by*32 + ty*2, cb = bx*32 + tx*2;
  C[(size_t)(ca+0)*co + cb+0]=a00; C[(size_t)(ca+0)*co + cb+1]=a01;
  C[(size_t)(ca+1)*co + cb+0]=a10; C[(size_t)(ca+1)*co + cb+1]=a11;
}

__global__ void k_layerinit(int* bnd, uint32_t* ctrlU, int* ctrlI){
  const int dim = blockIdx.x;
  for (int i=threadIdx.x;i<NN;i+=blockDim.x) bnd[dim*NN+i] = 0;
  if (threadIdx.x==0){
    ctrlU[dim*8+0] = 0xFFFFFFFFu;
    ctrlU[dim*8+1] = 0u;
    ctrlI[dim*8+1] = 0;
    ctrlI[dim*8+3] = 0;
  }
}

// lo = max(amin - gersh(C), amax - theta - pad); coarse bins of width <= COARSE_H
__global__ __launch_bounds__(256) void k_bounds(const float* __restrict__ Cb,
                         const uint32_t* ctrlU, const float* __restrict__ thB,
                         float* ctrlF, int* ctrlI, int co){
  const int dim = blockIdx.x, tid = threadIdx.x;
  const float* C = Cb + (size_t)dim*co*co;
  __shared__ float red[4];
  float rs = 0.f;
  if (tid < co){
    const float* row = C + (size_t)tid*co;
    for (int b=0;b<co;b++) rs += fabsf(row[b]);
  }
  float mx = wredMax(rs);
  if ((tid&63)==0) red[tid>>6] = mx;
  __syncthreads();
  if (tid==0){
    const float gersh = fmaxf(fmaxf(red[0],red[1]), fmaxf(red[2],red[3]));
    const float amin = decF(ctrlU[dim*8+0]);
    const float amax = decF(ctrlU[dim*8+1]);
    const float th = thB[dim];
    const float loG = amin - gersh;
    const float loP = amax - th - (0.02f*fabsf(th) + 0.5f);
    const float lo = fmaxf(loG, loP) - 0.05f;
    const float hi = amax + 0.1f;
    int nb = (int)ceilf((hi - lo)/COARSE_H);
    if (nb > MAXB1) nb = MAXB1;
    if (nb < 8) nb = 8;
    ctrlF[dim*8+0] = lo;
    ctrlF[dim*8+1] = (hi - lo)/nb;   // h1
    ctrlI[dim*8+0] = nb;             // nb1
  }
}

__global__ void k_flags(const int* __restrict__ bnd, int* flags, int* cstart, int* ctrlI){
  const int dim = blockIdx.x;
  if (threadIdx.x) return;
  const int* b = bnd + dim*NN;
  int* f = flags + dim*NN;
  int* cs = cstart + dim*(NN+1);
  int cur = 0; f[0] = 0; cs[0] = 0;
  for (int i=1;i<NN;i++){
    cur += b[i-1];
    f[i] = cur;
    if (b[i-1]) cs[cur] = i;
  }
  ctrlI[dim*8+2] = cur+1;
  cs[cur+1] = NN;
}

__global__ void k_cavg(const float* __restrict__ g, const int* __restrict__ cstart,
                       const int* __restrict__ ctrlI, float* __restrict__ cavg, int co){
  const int dim = blockIdx.y;
  const int nc = ctrlI[dim*8+2];
  const float* gD = g + (size_t)dim*NN*co;
  const int cc = threadIdx.x;
  for (int c = blockIdx.x; c < nc; c += gridDim.x){
    const int s = cstart[dim*(NN+1)+c], e = cstart[dim*(NN+1)+c+1];
    const float inv = 1.0f/(float)(e - s);
    if (cc < co){
      float acc = 0.f;
      for (int i=s;i<e;i++) acc += gD[(size_t)i*co + cc];
      cavg[((size_t)dim*NN + c)*co + cc] = acc*inv;
    }
  }
}

__global__ void k_clin(const float* __restrict__ cavg, const float* __restrict__ linW,
                       const float* __restrict__ linb, float* __restrict__ clin,
                       const int* __restrict__ ctrlI, int co){
  const int dim = blockIdx.y;
  const int nc = ctrlI[dim*8+2];
  __shared__ float row[DMX];
  const int tid = threadIdx.x;
  for (int c = blockIdx.x; c < nc; c += gridDim.x){
    const float* av = cavg + ((size_t)dim*NN + c)*co;
    __syncthreads();
    if (tid < co) row[tid] = av[tid];
    __syncthreads();
    if (tid < co){
      float s = linb[tid];
      for (int k=0;k<co;k++) s = fmaf(row[k], linW[(size_t)k*co + tid], s);
      clin[((size_t)dim*NN + c)*co + tid] = s;
    }
  }
}

__global__ void k_out(const float* __restrict__ fir, const float* __restrict__ clin,
                      const int* __restrict__ flags, const float* __restrict__ ksv,
                      float* __restrict__ out, int co){
  const int i = blockIdx.x, dim = blockIdx.y, c = threadIdx.x;
  const float kv = ksv[0];
  const int cls = flags[dim*NN+i];
  const float fv = fir[((size_t)dim*NN+i)*co + c];
  const float lv = clin[((size_t)dim*NN+cls)*co + c];
  const float o = 2.f*fv + kv*lv;
  out[((size_t)dim*NN+i)*co + c] = (o > 0.f) ? o : 0.f;
}

__global__ void k_final(const float* __restrict__ outL, const float* __restrict__ dimw,
                        float* __restrict__ o){
  const int i = blockIdx.x, c = threadIdx.x;
  float w[ND]; float ws = 0.f;
#pragma unroll
  for (int d=0;d<ND;d++){ w[d] = dimw[d]; ws += w[d]; }
  float v = 0.f;
#pragma unroll
  for (int d=0;d<ND;d++) v += (w[d]/ws) * outL[((size_t)d*NN + i)*128 + c];
  o[(size_t)i*128 + c] = v;
}

// ============================ host ============================
extern "C" void kernel_launch(void* const* d_in, const int* in_sizes, int n_in,
                              void* d_out, int out_size, void* d_ws, size_t ws_size,
                              hipStream_t stream)
{
  const float* dims_in[ND];
  for (int d=0;d<ND;d++) dims_in[d] = (const float*)d_in[d];
  const int*   eidx = (const int*)d_in[5];
  const float* ew   = (const float*)d_in[6];
  const float* convW[6]; const float* convb[6];
  for (int l=0;l<6;l++){ convW[l] = (const float*)d_in[8+2*l]; convb[l] = (const float*)d_in[9+2*l]; }
  const float* linW[6]; const float* linb[6];
  for (int l=0;l<6;l++){ linW[l] = (const float*)d_in[20+2*l]; linb[l] = (const float*)d_in[21+2*l]; }
  const float* ch1W = (const float*)d_in[32]; const float* ch1b = (const float*)d_in[33];
  const float* ch2W = (const float*)d_in[34]; const float* ch2b = (const float*)d_in[35];
  const float* dimw = (const float*)d_in[36]; const float* ksv = (const float*)d_in[37];

  // ---- carve workspace ----
  char* p = (char*)d_ws;
  auto take = [&](size_t bytes)->char*{
    char* r = p; p += (bytes + 255) & ~(size_t)255; return r;
  };
  int*   csr_base = (int*)  take((size_t)ND*(NN+1)*4);
  int*   csr_cur  = (int*)  take((size_t)ND*NN*4);
  int*   csr_psrc = (int*)  take((size_t)ND*NE*4);
  float* csr_coef = (float*)take((size_t)ND*NE*4);
  float* deg      = (float*)take((size_t)ND*NN*4);
  float* selfw    = (float*)take((size_t)ND*NN*4);
  float* gA   = (float*)take((size_t)ND*NN*DMX*4);
  float* gB   = (float*)take((size_t)ND*NN*DMX*4);
  float* outA = (float*)take((size_t)ND*NN*DMX*4);
  float* outB = (float*)take((size_t)ND*NN*DMX*4);
  float* hbuf = (float*)take((size_t)ND*NN*DMX*4);
  float* xnbuf= (float*)take((size_t)ND*NN*DMX*4);
  float* cavg = (float*)take((size_t)ND*NN*DMX*4);
  uint16_t* xph = (uint16_t*)take((size_t)ND*NN*DMX*2);
  uint16_t* xpl = (uint16_t*)take((size_t)ND*NN*DMX*2);
  float* abuf = (float*)take((size_t)ND*NN*4);
  float* sbuf = (float*)take((size_t)ND*DMX*4);
  float* Cbuf = (float*)take((size_t)ND*DMX*DMX*4);
  float* vpow = (float*)take((size_t)ND*NN*4);
  float* zpartG=(float*)take((size_t)ND*16*DMX*4);
  float* scACC =(float*)take((size_t)2*ND*2*4);
  int*   nu1  = (int*)  take((size_t)ND*(MAXB1+2)*4);
  float* tus1 = (float*)take((size_t)ND*(MAXB1+2)*4);
  int*   nuF  = (int*)  take((size_t)ND*NBF*4);
  float* tusF = (float*)take((size_t)ND*NBF*4);
  int*   binSel=(int*)  take((size_t)ND*MAXB1*4);
  int*   fineBins=(int*)take((size_t)ND*NFMAX*4);
  int*   runP = (int*)  take((size_t)ND*MAXRUN*4);
  float* runB = (float*)take((size_t)ND*MAXRUN*4*4);
  int*   nuP  = (int*)  take((size_t)ND*MAXRUN*2*NPB*4);
  float* tP   = (float*)take((size_t)ND*MAXRUN*2*NPB*4);
  int*   bnd  = (int*)  take((size_t)ND*NN*4);
  int*   flagsA=(int*)  take((size_t)ND*NN*4);
  int*   cstart=(int*)  take((size_t)ND*(NN+1)*4);
  float* ctrlF= (float*)take((size_t)ND*8*4);
  uint32_t* ctrlU = (uint32_t*)take((size_t)ND*8*4);
  int*   ctrlI= (int*)  take((size_t)ND*8*4);
  float* thB  = (float*)take((size_t)ND*4);
  (void)ws_size; (void)in_sizes; (void)n_in; (void)out_size;

  // ---- allow >64KB dynamic LDS for the D=256 eval kernels ----
  {
    void (*pe)(const uint16_t*,const uint16_t*,const float*,const float*,const int*,int*,float*) = k_eval<256,640,1>;
    hipFuncSetAttribute((const void*)pe, hipFuncAttributeMaxDynamicSharedMemorySize, SMEM_D(256));
    void (*pf)(const uint16_t*,const uint16_t*,const float*,const float*,const int*,const int*,int*,float*) = k_evalF<256,640,1>;
    hipFuncSetAttribute((const void*)pf, hipFuncAttributeMaxDynamicSharedMemorySize, SMEM_D(256));
    void (*pp)(const uint16_t*,const uint16_t*,const float*,const int*,const int*,const float*,int*,float*) = k_probe<256,640,1>;
    hipFuncSetAttribute((const void*)pp, hipFuncAttributeMaxDynamicSharedMemorySize, SMEM_D(256));
  }

  // ---- CSR setup (edges fixed across layers) ----
  k_init<<<ND, 256, 0, stream>>>(deg, csr_cur);
  k_count<<<(ND*NE+255)/256, 256, 0, stream>>>(eidx, ew, deg, csr_cur);
  k_prefix<<<ND, 64, 0, stream>>>(csr_cur, csr_base);
  k_fill_csr<<<(ND*NE+255)/256, 256, 0, stream>>>(eidx, ew, deg, csr_cur, csr_psrc, csr_coef);
  k_selfw<<<(ND*NN+255)/256, 256, 0, stream>>>(deg, selfw);

  float* gbufs[2] = {gA, gB};
  float* obufs[2] = {outA, outB};
  const float* gPrev = nullptr;
  const float* oPrev = nullptr;

  for (int l=0;l<6;l++){
    const int co = (l==0) ? 256 : 128;
    const int ci = (l==0) ? 512 : ((l==1) ? 256 : 128);
    float* gCur = gbufs[l&1];
    float* oCur = obufs[l&1];

    if (l==0){
      for (int d=0;d<ND;d++)
        k_gemm<<<dim3(256/64, NN/64, 1), 256, 0, stream>>>(
          dims_in[d], 0, convW[0] + (size_t)d*512*256, 0, nullptr, 0,
          hbuf + (size_t)d*NN*256, 0, NN, 512, 256);
    } else {
      k_gemm<<<dim3(co/64, NN/64, ND), 256, 0, stream>>>(
        gPrev, (long long)NN*ci, convW[l], (long long)ci*co, nullptr, 0,
        hbuf, (long long)NN*co, NN, ci, co);
    }

    k_layerinit<<<ND, 256, 0, stream>>>(bnd, ctrlU, ctrlI);
    k_agg<<<dim3(NN, ND), co, 0, stream>>>(hbuf, gCur, convb[l], csr_base, csr_psrc,
                                           csr_coef, selfw, co);
    k_rownorm<<<dim3(NN, ND), 256, 0, stream>>>(gCur, xnbuf, co);
    k_prep<<<dim3(NN/8, ND), co, 0, stream>>>(xnbuf, xph, xpl, co);
    k_colsum<<<dim3(co/64, ND), 256, 0, stream>>>(xnbuf, sbuf, co);
    k_adot<<<dim3(NN/8, ND), 512, 0, stream>>>(xnbuf, sbuf, abuf, ctrlU, co);
    k_gramC<<<dim3((co/32)*(co/32), ND), 256, 0, stream>>>(xnbuf, Cbuf, co);

    // power iteration: 33 iterations, 2 micro-kernels each (z then y)
    k_pw_init<<<ND, 1024, 0, stream>>>(vpow, scACC);
    if (l==0){
      for (int it=0; it<33; it++){
        const int sp = it & 1, sc = sp ^ 1;
        k_pw_z<256><<<dim3(16, ND), 256, 0, stream>>>(xnbuf, vpow, zpartG, scACC, sc);
        k_pw_y<256><<<dim3(16, ND), 256, 0, stream>>>(xnbuf, abuf, ctrlU, zpartG, vpow, scACC, sp, sc);
      }
    } else {
      for (int it=0; it<33; it++){
        const int sp = it & 1, sc = sp ^ 1;
        k_pw_z<128><<<dim3(16, ND), 128, 0, stream>>>(xnbuf, vpow, zpartG, scACC, sc);
        k_pw_y<128><<<dim3(16, ND), 256, 0, stream>>>(xnbuf, abuf, ctrlU, zpartG, vpow, scACC, sp, sc);
      }
    }
    k_pw_fin<<<1, 64, 0, stream>>>(scACC, thB, 1);

    k_bounds<<<ND, 256, 0, stream>>>(Cbuf, ctrlU, thB, ctrlF, ctrlI, co);

    if (l==0){
      k_eval<256,640,1><<<dim3((MAXB1+2)/2, ND), 640, SMEM_D(256), stream>>>(xph, xpl, abuf, ctrlF, ctrlI, nu1, tus1);
      k_sel<<<dim3((MAXB1+255)/256, ND), 256, 0, stream>>>(nu1, ctrlI, binSel, fineBins);
      k_fill<<<dim3((NBF+255)/256, ND), 256, 0, stream>>>(nu1, tus1, binSel, ctrlF, ctrlI, nuF, tusF);
      k_evalF<256,640,1><<<dim3(NFMAX*4, ND), 640, SMEM_D(256), stream>>>(xph, xpl, abuf, ctrlF, ctrlI, fineBins, nuF, tusF);
      k_runs<<<dim3((NBF+255)/256, ND), 256, 0, stream>>>(nuF, tusF, ctrlI, runP, runB, bnd);
      k_probe<256,640,1><<<dim3(MAXRUN*4, ND), 640, SMEM_D(256), stream>>>(xph, xpl, abuf, ctrlI, runP, runB, nuP, tP);
      k_decide<<<ND, 256, 0, stream>>>(ctrlI, runP, runB, nuP, tP, bnd);
    } else {
      k_eval<128,192,4><<<dim3((MAXB1+2)/2, ND), 192, SMEM_D(128), stream>>>(xph, xpl, abuf, ctrlF, ctrlI, nu1, tus1);
      k_sel<<<dim3((MAXB1+255)/256, ND), 256, 0, stream>>>(nu1, ctrlI, binSel, fineBins);
      k_fill<<<dim3((NBF+255)/256, ND), 256, 0, stream>>>(nu1, tus1, binSel, ctrlF, ctrlI, nuF, tusF);
      k_evalF<128,192,4><<<dim3(NFMAX*4, ND), 192, SMEM_D(128), stream>>>(xph, xpl, abuf, ctrlF, ctrlI, fineBins, nuF, tusF);
      k_runs<<<dim3((NBF+255)/256, ND), 256, 0, stream>>>(nuF, tusF, ctrlI, runP, runB, bnd);
      k_probe<128,192,4><<<dim3(MAXRUN*4, ND), 192, SMEM_D(128), stream>>>(xph, xpl, abuf, ctrlI, runP, runB, nuP, tP);
      k_decide<<<ND, 256, 0, stream>>>(ctrlI, runP, runB, nuP, tP, bnd);
    }

    k_flags<<<ND, 64, 0, stream>>>(bnd, flagsA, cstart, ctrlI);
    k_cavg<<<dim3(128, ND), 256, 0, stream>>>(gCur, cstart, ctrlI, cavg, co);
    k_clin<<<dim3(128, ND), 256, 0, stream>>>(cavg, linW[l], linb[l], xnbuf, ctrlI, co);

    const float* firPtr;
    if (l==0){
      for (int d=0;d<ND;d++)
        k_gemm<<<dim3(256/64, NN/64, 1), 256, 0, stream>>>(
          dims_in[d], 0, ch1W, 0, ch1b, 0, hbuf + (size_t)d*NN*256, 0, NN, 512, 256);
      firPtr = hbuf;
    } else if (l==1){
      k_gemm<<<dim3(128/64, NN/64, ND), 256, 0, stream>>>(
        oPrev, (long long)NN*256, ch2W, 0, ch2b, 0, hbuf, (long long)NN*128, NN, 256, 128);
      firPtr = hbuf;
    } else {
      firPtr = oPrev;
    }

    k_out<<<dim3(NN, ND), co, 0, stream>>>(firPtr, xnbuf, flagsA, ksv, oCur, co);

    gPrev = gCur; oPrev = oCur;
  }

  k_final<<<NN, 128, 0, stream>>>(oPrev, dimw, (float*)d_out);
}

// Round 9
// 32992.676 us; speedup vs baseline: 3.5313x; 3.5313x over previous
//
#include <hip/hip_runtime.h>
#include <math.h>
#include <stdint.h>

#define NN 2048
#define NE 65536
#define ND 5
#define DMX 256
#define MAXB1 2048
#define SUBD 8
#define NBF (MAXB1*SUBD+1)
#define NFMAX 1536
#define MAXRUN 1536
#define NPB 4
#define COARSE_H 1.76f
#define NUDGE 2e-3f
#define THRG 0.5f

typedef float f32x16 __attribute__((ext_vector_type(16)));
typedef short s16x8 __attribute__((ext_vector_type(8)));
typedef unsigned short u16x8 __attribute__((ext_vector_type(8)));

// ============================ device helpers ============================
__device__ __forceinline__ float wredSum(float v){
#pragma unroll
  for (int o=32;o>0;o>>=1) v += __shfl_down(v,o,64);
  return v;
}
__device__ __forceinline__ float wredMin(float v){
#pragma unroll
  for (int o=32;o>0;o>>=1) v = fminf(v,__shfl_down(v,o,64));
  return v;
}
__device__ __forceinline__ float wredMax(float v){
#pragma unroll
  for (int o=32;o>0;o>>=1) v = fmaxf(v,__shfl_down(v,o,64));
  return v;
}
__device__ __forceinline__ uint32_t encF(float f){
  uint32_t u = __float_as_uint(f);
  return (u & 0x80000000u) ? ~u : (u | 0x80000000u);
}
__device__ __forceinline__ float decF(uint32_t u){
  return (u & 0x80000000u) ? __uint_as_float(u ^ 0x80000000u) : __uint_as_float(~u);
}
__device__ __forceinline__ uint16_t bf16hi(float f){
  return (uint16_t)(__float_as_uint(f)>>16);
}

template<int BLK>
__device__ float bredSum(float v, float* red){
  v = wredSum(v);
  const int w = threadIdx.x >> 6;
  if ((threadIdx.x & 63) == 0) red[w] = v;
  __syncthreads();
  if (threadIdx.x == 0){
    float s = 0.f;
#pragma unroll
    for (int i=0;i<BLK/64;i++) s += red[i];
    red[0] = s;
  }
  __syncthreads();
  float r = red[0];
  __syncthreads();
  return r;
}

// precompute bf16 hi/lo split of X in chunk-transposed staged layout:
// XPH8[((dim*(NN/8)) + c2)*co + col] = u16x8 of rows c2*8..c2*8+7, column col
__global__ void k_prep(const float* __restrict__ xn, uint16_t* __restrict__ xph,
                       uint16_t* __restrict__ xpl, int co){
  const int dim = blockIdx.y;
  const int c2 = blockIdx.x;           // 0..NN/8-1
  const int col = threadIdx.x;         // 0..co-1
  const float* x = xn + (size_t)dim*NN*co;
  const int kb = c2*8;
  u16x8 h8, l8;
#pragma unroll
  for (int j=0;j<8;j++){
    const float x0 = x[(size_t)(kb+j)*co + col];
    const uint16_t h = bf16hi(x0);
    h8[j] = h;
    l8[j] = bf16hi(x0 - __uint_as_float((uint32_t)h<<16));
  }
  const size_t o = ((size_t)dim*(NN/8) + c2)*co + col;
  reinterpret_cast<u16x8*>(xph)[o] = h8;
  reinterpret_cast<u16x8*>(xpl)[o] = l8;
}

// ============================ nu(t) evaluation ============================
// nu(t) = #{eig(L) < t} = #{a_i < t} + n_-( I - X^T diag(1/(a-t)) X )
// Gram: bf16x3 split-precision MFMA (v_mfma_f32_32x32x16_bf16, short8 frags).
//   X's bf16 hi/lo split precomputed per layer (k_prep); staging = 2 coalesced
//   u16x8 loads + LDS copy; only the t-dependent w-path is computed here.
//   LDS arrays XTh/XTl/WXh/WXl ([col][k], stride 24 u16 => 48B rows),
//   one wave owns one 2x2 block of 32x32 output tiles, 3 passes.
// Inertia: panel-8 blocked LDL^T.
//   Panel: lane0 factors the 8x8 diagonal block in registers (counts pivot
//   signs), publishes 36 multipliers + 8 inv-pivots to LDS scratch; then all
//   64 lanes of wave0 solve trailing rows IN PARALLEL (8-step register
//   triangular solve per row). Trailing: parallel rank-8 update, 2 barriers.
// NOTE: a two-t-per-block variant was tried (R8) and regressed 3.5x: the
// second t's 8 f32x16 accumulators (128 VGPRs) live across the first LDL^T
// overflow the register budget -> scratch spills. Keep single-t.
template<int D, int BLK>
__device__ int evalNu(const uint16_t* __restrict__ xph, const uint16_t* __restrict__ xpl,
                      const float* __restrict__ a,
                      float t0, float dlt,
                      float* M, float* Pt, float* red, float* wrow,
                      float* scal, float* tOut)
{
  const int tid = threadIdx.x;
  float* fsc = scal + 16;   // 48-float panel-factor scratch

  // ---- phase 1a: nudge t away from poles a_i ----
  float md = 1e30f;
  for (int i=tid;i<NN;i+=BLK) md = fminf(md, fabsf(a[i]-t0));
  md = wredMin(md);
  if ((tid & 63) == 0) red[tid>>6] = md;
  __syncthreads();
  if (tid == 0){
    float m2 = 1e30f;
    for (int i=0;i<BLK/64;i++) m2 = fminf(m2, red[i]);
    scal[1] = (m2 < 1e-3f) ? (t0 + dlt) : t0;
  }
  __syncthreads();
  const float t = scal[1];
  __syncthreads();

  // ---- phase 1b: count a_i < t ----
  float c = 0.f;
  for (int i=tid;i<NN;i+=BLK) c += (a[i] < t) ? 1.f : 0.f;
  float cnt = bredSum<BLK>(c, red);

  // ---- phase 2: G = sum_i w_i x_i x_i^T via bf16x3 MFMA ----
  constexpr int BG  = D/64;            // 2x2-tile block grid dim
  constexpr int NBL = BG*(BG+1)/2;     // upper-tri blocks == waves
  constexpr int SXT = 24;              // u16 stride: K=16 + pad8 (48B rows)
  static_assert(BLK == NBL*64, "one wave per tile block");
  static_assert(4*D*SXT*2 <= (D*(D+1)/2)*4, "XT overlay fits in M");

  uint16_t* XTh = reinterpret_cast<uint16_t*>(M);
  uint16_t* XTl = XTh + D*SXT;
  uint16_t* WXh = XTl + D*SXT;
  uint16_t* WXl = WXh + D*SXT;
  const u16x8* XPH = reinterpret_cast<const u16x8*>(xph);
  const u16x8* XPL = reinterpret_cast<const u16x8*>(xpl);

  const int wv_ = tid >> 6, lane = tid & 63;
  int bi = 0, bj = 0;
  { int rem = wv_; while (rem >= BG - bi){ rem -= BG - bi; bi++; } bj = bi + rem; }
  const int colA = bi*64 + (lane & 31);
  const int colB = bj*64 + (lane & 31);
  const int kgo  = (lane >> 5) * 8;

  f32x16 acc0, acc1, acc2, acc3;
#pragma unroll
  for (int e=0;e<16;e++){ acc0[e]=0.f; acc1[e]=0.f; acc2[e]=0.f; acc3[e]=0.f; }

  // prologue: pole weights for chunk 0 (buffer 0)
  if (tid < 16){
    float den = a[tid] - t;
    if (fabsf(den) < 1e-5f) den = (den < 0.f) ? -1e-5f : 1e-5f;
    wrow[tid] = 1.0f/den;
  }

  for (int k0=0; k0<NN; k0+=16){
    __syncthreads();   // prev chunk's frag reads done; this chunk's wrow published
    const float* wcur = wrow + ((k0>>4)&1)*16;
    // stage: items = (kg 0..1) x (col 0..D-1); lane-consecutive cols
    for (int it = tid; it < 2*D; it += BLK){
      const int kg  = it / D;
      const int col = it - kg*D;
      const u16x8 xh8 = XPH[(size_t)((k0>>3)+kg)*D + col];
      const u16x8 xl8 = XPL[(size_t)((k0>>3)+kg)*D + col];
      const float4 w0 = *reinterpret_cast<const float4*>(&wcur[kg*8]);
      const float4 w1 = *reinterpret_cast<const float4*>(&wcur[kg*8+4]);
      const float wv[8] = {w0.x,w0.y,w0.z,w0.w,w1.x,w1.y,w1.z,w1.w};
      u16x8 sph, spl;
#pragma unroll
      for (int j=0;j<8;j++){
        const float hf = __uint_as_float((uint32_t)(uint16_t)xh8[j]<<16);
        const float lf = __uint_as_float((uint32_t)(uint16_t)xl8[j]<<16);
        const float p0 = wv[j]*(hf+lf);
        const uint16_t hp = bf16hi(p0);
        sph[j] = hp;
        spl[j] = bf16hi(p0 - __uint_as_float((uint32_t)hp<<16));
      }
      const int base = col*SXT + kg*8;
      *reinterpret_cast<u16x8*>(XTh + base) = xh8;
      *reinterpret_cast<u16x8*>(XTl + base) = xl8;
      *reinterpret_cast<u16x8*>(WXh + base) = sph;
      *reinterpret_cast<u16x8*>(WXl + base) = spl;
    }
    // next chunk's pole weights into the other buffer
    if (tid < 16 && k0+16 < NN){
      float den = a[k0+16+tid] - t;
      if (fabsf(den) < 1e-5f) den = (den < 0.f) ? -1e-5f : 1e-5f;
      wrow[((((k0>>4)+1)&1)<<4) + tid] = 1.0f/den;
    }
    __syncthreads();   // XT + next wrow ready
    const s16x8 ah0 = *reinterpret_cast<const s16x8*>(WXh + colA*SXT + kgo);
    const s16x8 ah1 = *reinterpret_cast<const s16x8*>(WXh + (colA+32)*SXT + kgo);
    const s16x8 al0 = *reinterpret_cast<const s16x8*>(WXl + colA*SXT + kgo);
    const s16x8 al1 = *reinterpret_cast<const s16x8*>(WXl + (colA+32)*SXT + kgo);
    const s16x8 bh0 = *reinterpret_cast<const s16x8*>(XTh + colB*SXT + kgo);
    const s16x8 bh1 = *reinterpret_cast<const s16x8*>(XTh + (colB+32)*SXT + kgo);
    const s16x8 bl0 = *reinterpret_cast<const s16x8*>(XTl + colB*SXT + kgo);
    const s16x8 bl1 = *reinterpret_cast<const s16x8*>(XTl + (colB+32)*SXT + kgo);
    // interleave the 4 independent acc chains to hide MFMA latency
    acc0 = __builtin_amdgcn_mfma_f32_32x32x16_bf16(ah0, bh0, acc0, 0,0,0);
    acc1 = __builtin_amdgcn_mfma_f32_32x32x16_bf16(ah0, bh1, acc1, 0,0,0);
    acc2 = __builtin_amdgcn_mfma_f32_32x32x16_bf16(ah1, bh0, acc2, 0,0,0);
    acc3 = __builtin_amdgcn_mfma_f32_32x32x16_bf16(ah1, bh1, acc3, 0,0,0);
    acc0 = __builtin_amdgcn_mfma_f32_32x32x16_bf16(ah0, bl0, acc0, 0,0,0);
    acc1 = __builtin_amdgcn_mfma_f32_32x32x16_bf16(ah0, bl1, acc1, 0,0,0);
    acc2 = __builtin_amdgcn_mfma_f32_32x32x16_bf16(ah1, bl0, acc2, 0,0,0);
    acc3 = __builtin_amdgcn_mfma_f32_32x32x16_bf16(ah1, bl1, acc3, 0,0,0);
    acc0 = __builtin_amdgcn_mfma_f32_32x32x16_bf16(al0, bh0, acc0, 0,0,0);
    acc1 = __builtin_amdgcn_mfma_f32_32x32x16_bf16(al0, bh1, acc1, 0,0,0);
    acc2 = __builtin_amdgcn_mfma_f32_32x32x16_bf16(al1, bh0, acc2, 0,0,0);
    acc3 = __builtin_amdgcn_mfma_f32_32x32x16_bf16(al1, bh1, acc3, 0,0,0);
  }
  __syncthreads();   // last frag reads done before M overwrite

  // ---- phase 2b: M = I - G, packed upper triangle (row-major) ----
  {
    const int rbase = 4*(lane>>5);
#pragma unroll
    for (int q=0;q<4;q++){
      const f32x16 A = (q==0)?acc0:((q==1)?acc1:((q==2)?acc2:acc3));
      const int ta = 2*bi + (q>>1), tb = 2*bj + (q&1);
      const int bb = tb*32 + (lane & 31);
#pragma unroll
      for (int r=0;r<16;r++){
        const int aa = ta*32 + (r&3) + 8*(r>>2) + rbase;
        if (aa <= bb)
          M[aa*D - (aa*(aa-1))/2 + (bb-aa)] = ((aa==bb)?1.f:0.f) - A[r];
      }
    }
  }

  // ---- phase 3: panel-8 blocked LDL^T ----
  constexpr int PS = 12;   // Pt stride: 48B -> 16B-aligned, bank-spread
  int neg = 0;   // meaningful on lane 0 only
  for (int k0=0; k0<D; k0+=8){
    const int k1 = k0+8;
    __syncthreads();    // prev trailing / phase-2b visible
    if (tid < 64){
      // step A: lane0 factors the 8x8 diagonal block in registers
      if (tid == 0){
        float B[8][8];
#pragma unroll
        for (int q=0;q<8;q++){
#pragma unroll
          for (int p=0;p<=q;p++){
            const int g = k0+p;
            B[p][q] = M[g*D - (g*(g-1))/2 + (k0+q-g)];
          }
        }
        float inv8[8];
#pragma unroll
        for (int q=0;q<8;q++){
          float d = B[q][q];
          if (d < 0.f) neg++;
          if (fabsf(d) < 1e-8f) d = (d<0.f)?-1e-8f:1e-8f;
          const float inv = 1.0f/d;
          inv8[q] = inv;
#pragma unroll
          for (int i=q+1;i<8;i++){
            const float f = B[q][i]*inv;
#pragma unroll
            for (int j=i;j<8;j++) B[i][j] = fmaf(-f, B[q][j], B[i][j]);
          }
        }
#pragma unroll
        for (int q=0;q<8;q++){
          fsc[36+q] = inv8[q];
#pragma unroll
          for (int p=0;p<=q;p++) fsc[(q*(q+1))/2 + p] = B[p][q];
        }
      }
      __asm__ __volatile__("s_waitcnt lgkmcnt(0)" ::: "memory");  // wave-sync publish
      // step B: all 64 lanes solve trailing rows in parallel
      float c8[36], iv8[8];
#pragma unroll
      for (int k=0;k<36;k++) c8[k] = fsc[k];
#pragma unroll
      for (int k=0;k<8;k++) iv8[k] = fsc[36+k];
      for (int j = k1 + tid; j < D; j += 64){
        float rv[8], pt[8];
#pragma unroll
        for (int q=0;q<8;q++){
          const int g = k0+q;
          rv[q] = M[g*D - (g*(g-1))/2 + (j-g)];
        }
#pragma unroll
        for (int q=0;q<8;q++){
          float v = rv[q];
#pragma unroll
          for (int p=0;p<q;p++) v = fmaf(-c8[(q*(q+1))/2 + p], pt[p], v);
          pt[q] = v * iv8[q];
          const int g = k0+q;
          M[g*D - (g*(g-1))/2 + (j-g)] = v;
          Pt[j*PS + q] = pt[q];
        }
      }
    }
    __syncthreads();    // publish panel rows + Pt
    if (k1 < D){
      constexpr int G = BLK/4;
      const int grp = tid / G, sub = tid % G;
      for (int i0=k1; i0<D; i0+=4){
        const int i = i0 + grp;          // D-k1 multiple of 8 -> valid
        float cq[8];
#pragma unroll
        for (int q=0;q<8;q++){
          const int g = k0+q;
          cq[q] = M[g*D - (g*(g-1))/2 + (i-g)];
        }
        const int offi = i*D - (i*(i-1))/2;
        for (int j=i+sub; j<D; j+=G){
          const float4 p0 = *reinterpret_cast<const float4*>(&Pt[j*PS + 0]);
          const float4 p1 = *reinterpret_cast<const float4*>(&Pt[j*PS + 4]);
          float v = M[offi + (j-i)];
          v = fmaf(-cq[0],p0.x,v); v = fmaf(-cq[1],p0.y,v);
          v = fmaf(-cq[2],p0.z,v); v = fmaf(-cq[3],p0.w,v);
          v = fmaf(-cq[4],p1.x,v); v = fmaf(-cq[5],p1.y,v);
          v = fmaf(-cq[6],p1.z,v); v = fmaf(-cq[7],p1.w,v);
          M[offi + (j-i)] = v;
        }
      }
    }
  }
  if (tid == 0) ((int*)scal)[5] = neg;
  __syncthreads();
  const int negAll = ((int*)scal)[5];
  __syncthreads();

  *tOut = t;
  return negAll + (int)(cnt + 0.5f);
}

#define SMEM_D(D) (((D)*((D)+1)/2 + 12*(D) + 112)*4)

// coarse grid eval
template<int D, int BLK, int WPE>
__global__ __launch_bounds__(BLK,WPE) void k_eval(const uint16_t* __restrict__ xph,
    const uint16_t* __restrict__ xpl,
    const float* __restrict__ ab, const float* __restrict__ ctrlF,
    const int* __restrict__ ctrlI, int* __restrict__ nu1, float* __restrict__ tus1)
{
  const int dim = blockIdx.y;
  const int b = blockIdx.x;
  if (b > ctrlI[dim*8+0]) return;
  extern __shared__ float smem[];
  constexpr int TRI = D*(D+1)/2;
  float* M = smem; float* Pt = M+TRI; float* red = Pt + 12*D;
  float* wrow = red+16; float* scal = wrow+32;
  const float lo = ctrlF[dim*8+0], h1 = ctrlF[dim*8+1];
  float tU;
  int v = evalNu<D,BLK>(xph + (size_t)dim*NN*D, xpl + (size_t)dim*NN*D,
                        ab + dim*NN, lo + h1*b, NUDGE,
                        M,Pt,red,wrow,scal,&tU);
  if (threadIdx.x == 0){ nu1[dim*(MAXB1+1)+b] = v; tus1[dim*(MAXB1+1)+b] = tU; }
}

// fine eval: SUBD-1 interior points per selected coarse bin
template<int D, int BLK, int WPE>
__global__ __launch_bounds__(BLK,WPE) void k_evalF(const uint16_t* __restrict__ xph,
    const uint16_t* __restrict__ xpl,
    const float* __restrict__ ab, const float* __restrict__ ctrlF,
    const int* __restrict__ ctrlI, const int* __restrict__ fineBins,
    int* __restrict__ nuF, float* __restrict__ tusF)
{
  const int dim = blockIdx.y;
  const int task = blockIdx.x / (SUBD-1);
  int cnt = ctrlI[dim*8+3]; if (cnt > NFMAX) cnt = NFMAX;
  if (task >= cnt) return;
  const int s = blockIdx.x % (SUBD-1) + 1;
  const int bin = fineBins[dim*NFMAX + task];
  extern __shared__ float smem[];
  constexpr int TRI = D*(D+1)/2;
  float* M = smem; float* Pt = M+TRI; float* red = Pt + 12*D;
  float* wrow = red+16; float* scal = wrow+32;
  const float lo = ctrlF[dim*8+0], hf = ctrlF[dim*8+1]*(1.0f/SUBD);
  const int f = bin*SUBD + s;
  float tU;
  int v = evalNu<D,BLK>(xph + (size_t)dim*NN*D, xpl + (size_t)dim*NN*D,
                        ab + dim*NN, lo + hf*f, NUDGE,
                        M,Pt,red,wrow,scal,&tU);
  if (threadIdx.x == 0){ nuF[(size_t)dim*NBF+f] = v; tusF[(size_t)dim*NBF+f] = tU; }
}

// one-shot probes: NPB points per side per ambiguous run, all parallel
template<int D, int BLK, int WPE>
__global__ __launch_bounds__(BLK,WPE) void k_probe(const uint16_t* __restrict__ xph,
    const uint16_t* __restrict__ xpl,
    const float* __restrict__ ab, const int* __restrict__ ctrlI,
    const int* __restrict__ runP, const float* __restrict__ runB,
    int* __restrict__ nuP, float* __restrict__ tP)
{
  const int dim = blockIdx.y;
  const int r = blockIdx.x >> 3;
  int nr = ctrlI[dim*8+1]; if (nr > MAXRUN) nr = MAXRUN;
  if (r >= nr) return;
  const int side = (blockIdx.x >> 2) & 1;
  const int i = blockIdx.x & 3;
  extern __shared__ float smem[];
  constexpr int TRI = D*(D+1)/2;
  float* M = smem; float* Pt = M+TRI; float* red = Pt + 12*D;
  float* wrow = red+16; float* scal = wrow+32;
  const float* rb = runB + (size_t)(dim*MAXRUN + r)*4;
  const float lo = rb[side*2+0], hi = rb[side*2+1];
  const float t0 = lo + (hi - lo)*(float)(i+1)*(1.0f/(NPB+1));
  const float dlt = fminf(NUDGE, (hi-lo)*0.08f);
  float tU;
  int v = evalNu<D,BLK>(xph + (size_t)dim*NN*D, xpl + (size_t)dim*NN*D,
                        ab + dim*NN, t0, dlt,
                        M,Pt,red,wrow,scal,&tU);
  if (threadIdx.x == 0){
    const size_t o = (((size_t)dim*MAXRUN + r)*2 + side)*NPB + i;
    nuP[o] = v; tP[o] = tU;
  }
}

__global__ void k_decide(const int* __restrict__ ctrlI, const int* __restrict__ runP,
                         const float* __restrict__ runB, const int* __restrict__ nuP,
                         const float* __restrict__ tP, int* __restrict__ bnd){
  const int dim = blockIdx.x;
  int nr = ctrlI[dim*8+1]; if (nr > MAXRUN) nr = MAXRUN;
  for (int r = threadIdx.x; r < nr; r += blockDim.x){
    const int p = runP[dim*MAXRUN + r];
    const float* rb = runB + (size_t)(dim*MAXRUN + r)*4;
    float lam[2];
    for (int side=0; side<2; side++){
      const int rank = p + side;   // nu(t) >= rank  <=>  lam_rank < t
      const size_t o = (((size_t)dim*MAXRUN + r)*2 + side)*NPB;
      float prev = rb[side*2+0];
      bool found = false; float l = 0.f;
      for (int i=0;i<NPB;i++){
        const float ti = tP[o+i];
        if (nuP[o+i] >= rank){ l = 0.5f*(prev + ti); found = true; break; }
        prev = ti;
      }
      if (!found) l = 0.5f*(prev + rb[side*2+1]);
      lam[side] = l;
    }
    if (lam[1] - lam[0] > THRG) bnd[dim*NN + p - 1] = 1;
  }
}

// select nonempty coarse bins for subdivision (parallel, atomic append)
__global__ void k_sel(const int* __restrict__ nu1, int* ctrlI,
                      int* __restrict__ binSel, int* __restrict__ fineBins){
  const int dim = blockIdx.y;
  const int j = blockIdx.x*256 + threadIdx.x;
  const int nb1 = ctrlI[dim*8+0];
  if (j >= nb1) return;
  const int* nv = nu1 + dim*(MAXB1+1);
  if (nv[j+1] != nv[j]){
    const int slot = atomicAdd(&ctrlI[dim*8+3], 1);
    if (slot < NFMAX){ binSel[dim*MAXB1+j] = slot; fineBins[dim*NFMAX+slot] = j; }
    else binSel[dim*MAXB1+j] = -2;
  } else binSel[dim*MAXB1+j] = -1;
}

// fill combined fine-resolution arrays (fine eval overwrites its slots after)
__global__ void k_fill(const int* __restrict__ nu1, const float* __restrict__ tus1,
                       const int* __restrict__ binSel, const float* __restrict__ ctrlF,
                       const int* __restrict__ ctrlI,
                       int* __restrict__ nuF, float* __restrict__ tusF){
  const int dim = blockIdx.y;
  const int f = blockIdx.x*256 + threadIdx.x;
  const int nb1 = ctrlI[dim*8+0];
  if (f > nb1*SUBD) return;
  const int j = f / SUBD, s = f % SUBD;
  const float lo = ctrlF[dim*8+0], hf = ctrlF[dim*8+1]*(1.0f/SUBD);
  int v; float tv;
  if (s == 0){ v = nu1[dim*(MAXB1+1)+j]; tv = tus1[dim*(MAXB1+1)+j]; }
  else {
    const int sel = binSel[dim*MAXB1+j];
    tv = lo + hf*f;
    if (sel == -2) v = 0x40000000 + f;       // sentinel: suppress runs here
    else v = nu1[dim*(MAXB1+1)+j];           // empty bin: exact by monotonicity
  }
  nuF[(size_t)dim*NBF+f] = v;
  tusF[(size_t)dim*NBF+f] = tv;
}

// parallel run detection on the merged fine array.
// Span early-exit: tu monotone => once scanned span > THRG the final gmin
// must exceed THRG too -> decide bnd=1 without finding the true run end.
__global__ void k_runs(const int* __restrict__ nuF, const float* __restrict__ tusF,
                       int* ctrlI, int* __restrict__ runP, float* __restrict__ runB,
                       int* __restrict__ bnd){
  const int dim = blockIdx.y;
  const int b1 = blockIdx.x*256 + threadIdx.x;
  const int nbt = ctrlI[dim*8+0]*SUBD;
  if (b1 >= nbt) return;
  const int* nv = nuF + (size_t)dim*NBF;
  const float* tu = tusF + (size_t)dim*NBF;
  if (nv[b1+1] != nv[b1]) return;              // not an empty bin
  if (b1 > 0 && nv[b1-1] == nv[b1]) return;    // not the run start
  const int p = nv[b1];
  if (p < 1 || p > NN-1 || b1 < 1) return;     // reject BEFORE the scan
  const float tb1 = tu[b1];
  int j2 = b1;
  while (j2+1 < nbt && nv[j2+2] == nv[j2+1]){
    j2++;
    if (tu[j2+1] - tb1 > THRG){ bnd[dim*NN + p-1] = 1; return; }
  }
  if (j2 > nbt-2) return;
  const float gmin = tu[j2+1] - tb1;
  const float gmax = tu[j2+2] - tu[b1-1];
  if (gmin > THRG){ bnd[dim*NN + p-1] = 1; return; }
  if (gmax > THRG){
    const int slot = atomicAdd(&ctrlI[dim*8+1], 1);
    if (slot < MAXRUN){
      runP[dim*MAXRUN + slot] = p;
      float* rb = runB + (size_t)(dim*MAXRUN + slot)*4;
      rb[0]=tu[b1-1]; rb[1]=tu[b1]; rb[2]=tu[j2+1]; rb[3]=tu[j2+2];
    }
  }
}

// ============================ power iteration (multi-launch) ============
// Same recurrence as the fused version: v raw, y = invPrev*(ash*v + x.z),
// z = X^T v.  Split per iteration into a z-partial kernel (16 row segs/dim)
// and a y kernel (reduce z + update rows + n2/ray atomics). Ping-pong
// accumulator slots; invPrev = rsqrt(n2_prev), slot0 init = 1 (matches the
// fused version's first-iteration invPrev = 1).
__global__ void k_pw_init(float* __restrict__ vG, float* __restrict__ scACC){
  const int dim = blockIdx.x, tid = threadIdx.x;
  float* v = vG + (size_t)dim*NN;
  for (int i=tid;i<NN;i+=1024){
    uint32_t hsh = (uint32_t)i*2654435761u;
    v[i] = 1.0f + 2e-4f*(float)(hsh>>20);
  }
  if (tid == 0){ scACC[0*ND*2 + dim*2 + 0] = 1.0f; scACC[0*ND*2 + dim*2 + 1] = 0.f; }
}

template<int D>
__global__ __launch_bounds__(D) void k_pw_z(const float* __restrict__ xnb,
    const float* __restrict__ vG, float* __restrict__ zpart,
    float* __restrict__ scACC, int parReset){
  const int dim = blockIdx.y, seg = blockIdx.x, c = threadIdx.x;
  const float* x = xnb + (size_t)dim*NN*D;
  const float* v = vG + (size_t)dim*NN;
  const int i0 = seg*(NN/16);
  float acc = 0.f;
  for (int r=0;r<NN/16;r++){
    const int i = i0 + r;
    acc = fmaf(x[(size_t)i*D + c], v[i], acc);
  }
  zpart[((size_t)dim*16 + seg)*DMX + c] = acc;
  if (seg == 0 && c < 2) scACC[parReset*ND*2 + dim*2 + c] = 0.f;
}

template<int D>
__global__ __launch_bounds__(256) void k_pw_y(const float* __restrict__ xnb,
    const float* __restrict__ ab, const uint32_t* __restrict__ ctrlU,
    const float* __restrict__ zpart, float* __restrict__ vG,
    float* __restrict__ scACC, int parPrev, int parCur){
  constexpr int VEC = D/64;
  const int dim = blockIdx.y, seg = blockIdx.x, tid = threadIdx.x;
  const int w = tid >> 6, lane = tid & 63;
  const float* x = xnb + (size_t)dim*NN*D;
  const float* a = ab + dim*NN;
  float* v = vG + (size_t)dim*NN;
  __shared__ float zs[DMX];
  __shared__ float redn[4], redr[4];
  if (tid < D){
    float s = 0.f;
#pragma unroll
    for (int k=0;k<16;k++) s += zpart[((size_t)dim*16 + k)*DMX + tid];
    zs[tid] = s;
  }
  __syncthreads();
  const float amax = decF(ctrlU[dim*8+1]);
  const float invPrev = rsqrtf(fmaxf(scACC[parPrev*ND*2 + dim*2 + 0], 1e-30f));
  float zr[VEC];
#pragma unroll
  for (int k=0;k<VEC;k++) zr[k] = zs[lane*VEC + k];
  float n2 = 0.f, ray = 0.f;
  for (int r=0;r<32;r++){
    const int i = seg*(NN/16) + w*32 + r;
    const float* xr = x + (size_t)i*D + lane*VEC;
    float dot = 0.f;
#pragma unroll
    for (int k=0;k<VEC;k++) dot = fmaf(xr[k], zr[k], dot);
#pragma unroll
    for (int o=32;o>0;o>>=1) dot += __shfl_xor(dot,o,64);
    if (lane == 0){
      const float vr = v[i];
      const float y = invPrev * fmaf(amax - a[i], vr, dot);
      n2 = fmaf(y,y,n2); ray = fmaf(vr*invPrev, y, ray);
      v[i] = y;
    }
  }
  if (lane == 0){ redn[w] = n2; redr[w] = ray; }
  __syncthreads();
  if (tid == 0){
    float sn = redn[0]+redn[1]+redn[2]+redn[3];
    float sr = redr[0]+redr[1]+redr[2]+redr[3];
    atomicAdd(&scACC[parCur*ND*2 + dim*2 + 0], sn);
    atomicAdd(&scACC[parCur*ND*2 + dim*2 + 1], sr);
  }
}

__global__ void k_pw_fin(const float* __restrict__ scACC, float* __restrict__ thB,
                         int slot){
  if (threadIdx.x < ND) thB[threadIdx.x] = scACC[slot*ND*2 + threadIdx.x*2 + 1];
}

// ============================ graph / GCN kernels ============================
__global__ void k_init(float* deg, int* cur){
  const int dim = blockIdx.x;
  for (int i=threadIdx.x;i<NN;i+=blockDim.x){ deg[dim*NN+i] = 1.0f; cur[dim*NN+i] = 0; }
}
__global__ void k_count(const int* __restrict__ eidx, const float* __restrict__ ew,
                        float* deg, int* cur){
  const int idx = blockIdx.x*256 + threadIdx.x;
  if (idx >= ND*NE) return;
  const int dim = idx / NE, e = idx % NE;
  const int dst = eidx[(size_t)dim*2*NE + NE + e];
  atomicAdd(&cur[dim*NN + dst], 1);
  atomicAdd(&deg[dim*NN + dst], ew[(size_t)dim*NE + e]);
}
__global__ void k_prefix(int* cur, int* base){
  const int dim = blockIdx.x;
  if (threadIdx.x) return;
  int* b = base + dim*(NN+1);
  int* cc = cur + dim*NN;
  int run = 0; b[0] = 0;
  for (int i=0;i<NN;i++){ int cnt = cc[i]; cc[i] = run; b[i+1] = run + cnt; run += cnt; }
}
__global__ void k_fill_csr(const int* __restrict__ eidx, const float* __restrict__ ew,
                       const float* __restrict__ deg, int* cur, int* psrc, float* coef){
  const int idx = blockIdx.x*256 + threadIdx.x;
  if (idx >= ND*NE) return;
  const int dim = idx / NE, e = idx % NE;
  const int src = eidx[(size_t)dim*2*NE + e];
  const int dst = eidx[(size_t)dim*2*NE + NE + e];
  const int slot = atomicAdd(&cur[dim*NN + dst], 1);
  psrc[(size_t)dim*NE + slot] = src;
  const float ds = deg[dim*NN + src], dd = deg[dim*NN + dst];
  coef[(size_t)dim*NE + slot] = ew[(size_t)dim*NE + e] * (1.0f/sqrtf(ds)) * (1.0f/sqrtf(dd));
}
__global__ void k_selfw(const float* deg, float* sw){
  const int idx = blockIdx.x*256 + threadIdx.x;
  if (idx < ND*NN) sw[idx] = 1.0f/deg[idx];
}

// generic tiled GEMM: C[M,P] = A[M,K] @ W[K,P] (+bias). grid z = dim axis.
__global__ __launch_bounds__(256) void k_gemm(const float* __restrict__ A, long long aStr,
    const float* __restrict__ W, long long wStr,
    const float* __restrict__ bias, long long bStr,
    float* __restrict__ C, long long cStr, int M, int K, int P)
{
  const int dim = blockIdx.z;
  A += (size_t)dim*aStr; W += (size_t)dim*wStr; C += (size_t)dim*cStr;
  if (bias) bias += (size_t)dim*bStr;
  __shared__ float As[64][17];
  __shared__ float Bs[16][68];
  const int tid = threadIdx.x;
  const int tx = tid % 16, ty = tid / 16;
  const int m0 = blockIdx.y*64, p0 = blockIdx.x*64;
  float acc[4][4] = {};
  for (int k0=0;k0<K;k0+=16){
    __syncthreads();
    { int r = tid/4, c4 = (tid%4)*4;
      float4 v = *reinterpret_cast<const float4*>(A + (size_t)(m0+r)*K + k0 + c4);
      As[r][c4]=v.x; As[r][c4+1]=v.y; As[r][c4+2]=v.z; As[r][c4+3]=v.w; }
    { int r = tid/16, c4 = (tid%16)*4;
      float4 v = *reinterpret_cast<const float4*>(W + (size_t)(k0+r)*P + p0 + c4);
      Bs[r][c4]=v.x; Bs[r][c4+1]=v.y; Bs[r][c4+2]=v.z; Bs[r][c4+3]=v.w; }
    __syncthreads();
#pragma unroll
    for (int kk=0;kk<16;kk++){
      float a0=As[ty*4+0][kk], a1=As[ty*4+1][kk], a2=As[ty*4+2][kk], a3=As[ty*4+3][kk];
      float b0=Bs[kk][tx*4+0], b1=Bs[kk][tx*4+1], b2=Bs[kk][tx*4+2], b3=Bs[kk][tx*4+3];
      acc[0][0]=fmaf(a0,b0,acc[0][0]); acc[0][1]=fmaf(a0,b1,acc[0][1]);
      acc[0][2]=fmaf(a0,b2,acc[0][2]); acc[0][3]=fmaf(a0,b3,acc[0][3]);
      acc[1][0]=fmaf(a1,b0,acc[1][0]); acc[1][1]=fmaf(a1,b1,acc[1][1]);
      acc[1][2]=fmaf(a1,b2,acc[1][2]); acc[1][3]=fmaf(a1,b3,acc[1][3]);
      acc[2][0]=fmaf(a2,b0,acc[2][0]); acc[2][1]=fmaf(a2,b1,acc[2][1]);
      acc[2][2]=fmaf(a2,b2,acc[2][2]); acc[2][3]=fmaf(a2,b3,acc[2][3]);
      acc[3][0]=fmaf(a3,b0,acc[3][0]); acc[3][1]=fmaf(a3,b1,acc[3][1]);
      acc[3][2]=fmaf(a3,b2,acc[3][2]); acc[3][3]=fmaf(a3,b3,acc[3][3]);
    }
  }
  for (int i=0;i<4;i++){
    for (int j=0;j<4;j++){
      const int pp = p0 + tx*4 + j;
      float v = acc[i][j];
      if (bias) v += bias[pp];
      C[(size_t)(m0+ty*4+i)*P + pp] = v;
    }
  }
}

__global__ void k_agg(const float* __restrict__ h, float* __restrict__ g,
                      const float* __restrict__ convb, const int* __restrict__ base,
                      const int* __restrict__ psrc, const float* __restrict__ coef,
                      const float* __restrict__ selfw, int co)
{
  const int i = blockIdx.x, dim = blockIdx.y, c = threadIdx.x;
  const float* hD = h + (size_t)dim*NN*co;
  const int s = base[dim*(NN+1)+i], e = base[dim*(NN+1)+i+1];
  const int* ps = psrc + (size_t)dim*NE;
  const float* cf = coef + (size_t)dim*NE;
  float acc = 0.f;
  for (int q=s;q<e;q++) acc += cf[q]*hD[(size_t)ps[q]*co + c];
  g[((size_t)dim*NN+i)*co + c] = acc + hD[(size_t)i*co + c]*selfw[dim*NN+i] + convb[dim*co + c];
}

__global__ void k_rownorm(const float* __restrict__ g, float* __restrict__ xn, int co){
  const int i = blockIdx.x, dim = blockIdx.y;
  const float* gr = g + ((size_t)dim*NN+i)*co;
  float* xr = xn + ((size_t)dim*NN+i)*co;
  float p = 0.f;
  for (int c=threadIdx.x;c<co;c+=256){ float v = gr[c]; p += v*v; }
  __shared__ float red[4];
  p = wredSum(p);
  if ((threadIdx.x&63)==0) red[threadIdx.x>>6] = p;
  __syncthreads();
  if (threadIdx.x==0) red[0] = red[0]+red[1]+red[2]+red[3];
  __syncthreads();
  const float inv = 1.0f/(sqrtf(red[0]) + 1e-8f);
  for (int c=threadIdx.x;c<co;c+=256) xr[c] = gr[c]*inv;
}

// 256 threads: 4-way row-split partial sums + LDS reduce
__global__ void k_colsum(const float* __restrict__ xn, float* __restrict__ sb, int co){
  const int lane = threadIdx.x & 63;
  const int seg  = threadIdx.x >> 6;           // 0..3
  const int c = blockIdx.x*64 + lane;
  const int dim = blockIdx.y;
  const float* x = xn + (size_t)dim*NN*co;
  float s = 0.f;
  for (int i=seg*(NN/4); i<(seg+1)*(NN/4); i++) s += x[(size_t)i*co + c];
  __shared__ float part[4][64];
  part[seg][lane] = s;
  __syncthreads();
  if (threadIdx.x < 64)
    sb[dim*DMX + c] = part[0][lane]+part[1][lane]+part[2][lane]+part[3][lane];
}

// wave-per-row; 8 rows/block; one atomic pair per block
__global__ __launch_bounds__(512) void k_adot(const float* __restrict__ xn,
                       const float* __restrict__ sb,
                       float* __restrict__ ab, uint32_t* ctrlU, int co){
  const int dim = blockIdx.y;
  const int w = threadIdx.x >> 6, lane = threadIdx.x & 63;
  const int i = blockIdx.x*8 + w;
  const float* x = xn + ((size_t)dim*NN + i)*co;
  const float* s = sb + dim*DMX;
  float p = 0.f;
  for (int c=lane;c<co;c+=64) p = fmaf(x[c], s[c], p);
  p = wredSum(p);
  __shared__ uint32_t rmn[8], rmx[8];
  if (lane==0){
    ab[dim*NN+i] = p;
    const uint32_t e = encF(p);
    rmn[w] = e; rmx[w] = e;
  }
  __syncthreads();
  if (threadIdx.x==0){
    uint32_t mn = rmn[0], mx = rmx[0];
#pragma unroll
    for (int k=1;k<8;k++){
      mn = (rmn[k] < mn) ? rmn[k] : mn;
      mx = (rmx[k] > mx) ? rmx[k] : mx;
    }
    atomicMin(&ctrlU[dim*8+0], mn);
    atomicMax(&ctrlU[dim*8+1], mx);
  }
}

__global__ __launch_bounds__(256) void k_gramC(const float* __restrict__ xn,
                                               float* __restrict__ Cb, int co){
  const int dim = blockIdx.y;
  const int nbx = co/32;
  const int bx = blockIdx.x % nbx, by = blockIdx.x / nbx;
  const float* x = xn + (size_t)dim*NN*co;
  float* C = Cb + (size_t)dim*co*co;
  __shared__ float Xa[64][33];
  __shared__ float Xb[64][33];
  const int tid = threadIdx.x;
  const int ty = tid/16, tx = tid%16;
  float a00=0,a01=0,a10=0,a11=0;
  for (int i0=0;i0<NN;i0+=64){
    __syncthreads();
    for (int l=tid;l<512;l+=256){
      const int r = l/8, c4 = (l%8)*4;
      float4 va = *reinterpret_cast<const float4*>(x + (size_t)(i0+r)*co + by*32 + c4);
      Xa[r][c4]=va.x; Xa[r][c4+1]=va.y; Xa[r][c4+2]=va.z; Xa[r][c4+3]=va.w;
      float4 vb = *reinterpret_cast<const float4*>(x + (size_t)(i0+r)*co + bx*32 + c4);
      Xb[r][c4]=vb.x; Xb[r][c4+1]=vb.y; Xb[r][c4+2]=vb.z; Xb[r][c4+3]=vb.w;
    }
    __syncthreads();
#pragma unroll 8
    for (int r=0;r<64;r++){
      const float u0=Xa[r][ty*2], u1=Xa[r][ty*2+1], w0=Xb[r][tx*2], w1=Xb[r][tx*2+1];
      a00=fmaf(u0,w0,a00); a01=fmaf(u0,w1,a01); a10=fmaf(u1,w0,a10); a11=fmaf(u1,w1,a11);
    }
  }
  const int ca = by*32 + ty*2, cb = bx*32 + tx*2;
  C[(size_t)(ca+0)*co + cb+0]=a00; C[(size_t)(ca+0)*co + cb+1]=a01;
  C[(size_t)(ca+1)*co + cb+0]=a10; C[(size_t)(ca+1)*co + cb+1]=a11;
}

__global__ void k_layerinit(int* bnd, uint32_t* ctrlU, int* ctrlI){
  const int dim = blockIdx.x;
  for (int i=threadIdx.x;i<NN;i+=blockDim.x) bnd[dim*NN+i] = 0;
  if (threadIdx.x==0){
    ctrlU[dim*8+0] = 0xFFFFFFFFu;
    ctrlU[dim*8+1] = 0u;
    ctrlI[dim*8+1] = 0;
    ctrlI[dim*8+3] = 0;
  }
}

// lo = max(amin - gersh(C), amax - theta - pad); coarse bins of width <= COARSE_H
__global__ __launch_bounds__(256) void k_bounds(const float* __restrict__ Cb,
                         const uint32_t* ctrlU, const float* __restrict__ thB,
                         float* ctrlF, int* ctrlI, int co){
  const int dim = blockIdx.x, tid = threadIdx.x;
  const float* C = Cb + (size_t)dim*co*co;
  __shared__ float red[4];
  float rs = 0.f;
  if (tid < co){
    const float* row = C + (size_t)tid*co;
    for (int b=0;b<co;b++) rs += fabsf(row[b]);
  }
  float mx = wredMax(rs);
  if ((tid&63)==0) red[tid>>6] = mx;
  __syncthreads();
  if (tid==0){
    const float gersh = fmaxf(fmaxf(red[0],red[1]), fmaxf(red[2],red[3]));
    const float amin = decF(ctrlU[dim*8+0]);
    const float amax = decF(ctrlU[dim*8+1]);
    const float th = thB[dim];
    const float loG = amin - gersh;
    const float loP = amax - th - (0.02f*fabsf(th) + 0.5f);
    const float lo = fmaxf(loG, loP) - 0.05f;
    const float hi = amax + 0.1f;
    int nb = (int)ceilf((hi - lo)/COARSE_H);
    if (nb > MAXB1) nb = MAXB1;
    if (nb < 8) nb = 8;
    ctrlF[dim*8+0] = lo;
    ctrlF[dim*8+1] = (hi - lo)/nb;   // h1
    ctrlI[dim*8+0] = nb;             // nb1
  }
}

__global__ void k_flags(const int* __restrict__ bnd, int* flags, int* cstart, int* ctrlI){
  const int dim = blockIdx.x;
  if (threadIdx.x) return;
  const int* b = bnd + dim*NN;
  int* f = flags + dim*NN;
  int* cs = cstart + dim*(NN+1);
  int cur = 0; f[0] = 0; cs[0] = 0;
  for (int i=1;i<NN;i++){
    cur += b[i-1];
    f[i] = cur;
    if (b[i-1]) cs[cur] = i;
  }
  ctrlI[dim*8+2] = cur+1;
  cs[cur+1] = NN;
}

__global__ void k_cavg(const float* __restrict__ g, const int* __restrict__ cstart,
                       const int* __restrict__ ctrlI, float* __restrict__ cavg, int co){
  const int dim = blockIdx.y;
  const int nc = ctrlI[dim*8+2];
  const float* gD = g + (size_t)dim*NN*co;
  const int cc = threadIdx.x;
  for (int c = blockIdx.x; c < nc; c += gridDim.x){
    const int s = cstart[dim*(NN+1)+c], e = cstart[dim*(NN+1)+c+1];
    const float inv = 1.0f/(float)(e - s);
    if (cc < co){
      float acc = 0.f;
      for (int i=s;i<e;i++) acc += gD[(size_t)i*co + cc];
      cavg[((size_t)dim*NN + c)*co + cc] = acc*inv;
    }
  }
}

__global__ void k_clin(const float* __restrict__ cavg, const float* __restrict__ linW,
                       const float* __restrict__ linb, float* __restrict__ clin,
                       const int* __restrict__ ctrlI, int co){
  const int dim = blockIdx.y;
  const int nc = ctrlI[dim*8+2];
  __shared__ float row[DMX];
  const int tid = threadIdx.x;
  for (int c = blockIdx.x; c < nc; c += gridDim.x){
    const float* av = cavg + ((size_t)dim*NN + c)*co;
    __syncthreads();
    if (tid < co) row[tid] = av[tid];
    __syncthreads();
    if (tid < co){
      float s = linb[tid];
      for (int k=0;k<co;k++) s = fmaf(row[k], linW[(size_t)k*co + tid], s);
      clin[((size_t)dim*NN + c)*co + tid] = s;
    }
  }
}

__global__ void k_out(const float* __restrict__ fir, const float* __restrict__ clin,
                      const int* __restrict__ flags, const float* __restrict__ ksv,
                      float* __restrict__ out, int co){
  const int i = blockIdx.x, dim = blockIdx.y, c = threadIdx.x;
  const float kv = ksv[0];
  const int cls = flags[dim*NN+i];
  const float fv = fir[((size_t)dim*NN+i)*co + c];
  const float lv = clin[((size_t)dim*NN+cls)*co + c];
  const float o = 2.f*fv + kv*lv;
  out[((size_t)dim*NN+i)*co + c] = (o > 0.f) ? o : 0.f;
}

__global__ void k_final(const float* __restrict__ outL, const float* __restrict__ dimw,
                        float* __restrict__ o){
  const int i = blockIdx.x, c = threadIdx.x;
  float w[ND]; float ws = 0.f;
#pragma unroll
  for (int d=0;d<ND;d++){ w[d] = dimw[d]; ws += w[d]; }
  float v = 0.f;
#pragma unroll
  for (int d=0;d<ND;d++) v += (w[d]/ws) * outL[((size_t)d*NN + i)*128 + c];
  o[(size_t)i*128 + c] = v;
}

// ============================ host ============================
extern "C" void kernel_launch(void* const* d_in, const int* in_sizes, int n_in,
                              void* d_out, int out_size, void* d_ws, size_t ws_size,
                              hipStream_t stream)
{
  const float* dims_in[ND];
  for (int d=0;d<ND;d++) dims_in[d] = (const float*)d_in[d];
  const int*   eidx = (const int*)d_in[5];
  const float* ew   = (const float*)d_in[6];
  const float* convW[6]; const float* convb[6];
  for (int l=0;l<6;l++){ convW[l] = (const float*)d_in[8+2*l]; convb[l] = (const float*)d_in[9+2*l]; }
  const float* linW[6]; const float* linb[6];
  for (int l=0;l<6;l++){ linW[l] = (const float*)d_in[20+2*l]; linb[l] = (const float*)d_in[21+2*l]; }
  const float* ch1W = (const float*)d_in[32]; const float* ch1b = (const float*)d_in[33];
  const float* ch2W = (const float*)d_in[34]; const float* ch2b = (const float*)d_in[35];
  const float* dimw = (const float*)d_in[36]; const float* ksv = (const float*)d_in[37];

  // ---- carve workspace ----
  char* p = (char*)d_ws;
  auto take = [&](size_t bytes)->char*{
    char* r = p; p += (bytes + 255) & ~(size_t)255; return r;
  };
  int*   csr_base = (int*)  take((size_t)ND*(NN+1)*4);
  int*   csr_cur  = (int*)  take((size_t)ND*NN*4);
  int*   csr_psrc = (int*)  take((size_t)ND*NE*4);
  float* csr_coef = (float*)take((size_t)ND*NE*4);
  float* deg      = (float*)take((size_t)ND*NN*4);
  float* selfw    = (float*)take((size_t)ND*NN*4);
  float* gA   = (float*)take((size_t)ND*NN*DMX*4);
  float* gB   = (float*)take((size_t)ND*NN*DMX*4);
  float* outA = (float*)take((size_t)ND*NN*DMX*4);
  float* outB = (float*)take((size_t)ND*NN*DMX*4);
  float* hbuf = (float*)take((size_t)ND*NN*DMX*4);
  float* xnbuf= (float*)take((size_t)ND*NN*DMX*4);
  float* cavg = (float*)take((size_t)ND*NN*DMX*4);
  uint16_t* xph = (uint16_t*)take((size_t)ND*NN*DMX*2);
  uint16_t* xpl = (uint16_t*)take((size_t)ND*NN*DMX*2);
  float* abuf = (float*)take((size_t)ND*NN*4);
  float* sbuf = (float*)take((size_t)ND*DMX*4);
  float* Cbuf = (float*)take((size_t)ND*DMX*DMX*4);
  float* vpow = (float*)take((size_t)ND*NN*4);
  float* zpartG=(float*)take((size_t)ND*16*DMX*4);
  float* scACC =(float*)take((size_t)2*ND*2*4);
  int*   nu1  = (int*)  take((size_t)ND*(MAXB1+1)*4);
  float* tus1 = (float*)take((size_t)ND*(MAXB1+1)*4);
  int*   nuF  = (int*)  take((size_t)ND*NBF*4);
  float* tusF = (float*)take((size_t)ND*NBF*4);
  int*   binSel=(int*)  take((size_t)ND*MAXB1*4);
  int*   fineBins=(int*)take((size_t)ND*NFMAX*4);
  int*   runP = (int*)  take((size_t)ND*MAXRUN*4);
  float* runB = (float*)take((size_t)ND*MAXRUN*4*4);
  int*   nuP  = (int*)  take((size_t)ND*MAXRUN*2*NPB*4);
  float* tP   = (float*)take((size_t)ND*MAXRUN*2*NPB*4);
  int*   bnd  = (int*)  take((size_t)ND*NN*4);
  int*   flagsA=(int*)  take((size_t)ND*NN*4);
  int*   cstart=(int*)  take((size_t)ND*(NN+1)*4);
  float* ctrlF= (float*)take((size_t)ND*8*4);
  uint32_t* ctrlU = (uint32_t*)take((size_t)ND*8*4);
  int*   ctrlI= (int*)  take((size_t)ND*8*4);
  float* thB  = (float*)take((size_t)ND*4);
  (void)ws_size; (void)in_sizes; (void)n_in; (void)out_size;

  // ---- allow >64KB dynamic LDS for the D=256 eval kernels ----
  {
    void (*pe)(const uint16_t*,const uint16_t*,const float*,const float*,const int*,int*,float*) = k_eval<256,640,1>;
    hipFuncSetAttribute((const void*)pe, hipFuncAttributeMaxDynamicSharedMemorySize, SMEM_D(256));
    void (*pf)(const uint16_t*,const uint16_t*,const float*,const float*,const int*,const int*,int*,float*) = k_evalF<256,640,1>;
    hipFuncSetAttribute((const void*)pf, hipFuncAttributeMaxDynamicSharedMemorySize, SMEM_D(256));
    void (*pp)(const uint16_t*,const uint16_t*,const float*,const int*,const int*,const float*,int*,float*) = k_probe<256,640,1>;
    hipFuncSetAttribute((const void*)pp, hipFuncAttributeMaxDynamicSharedMemorySize, SMEM_D(256));
  }

  // ---- CSR setup (edges fixed across layers) ----
  k_init<<<ND, 256, 0, stream>>>(deg, csr_cur);
  k_count<<<(ND*NE+255)/256, 256, 0, stream>>>(eidx, ew, deg, csr_cur);
  k_prefix<<<ND, 64, 0, stream>>>(csr_cur, csr_base);
  k_fill_csr<<<(ND*NE+255)/256, 256, 0, stream>>>(eidx, ew, deg, csr_cur, csr_psrc, csr_coef);
  k_selfw<<<(ND*NN+255)/256, 256, 0, stream>>>(deg, selfw);

  float* gbufs[2] = {gA, gB};
  float* obufs[2] = {outA, outB};
  const float* gPrev = nullptr;
  const float* oPrev = nullptr;

  for (int l=0;l<6;l++){
    const int co = (l==0) ? 256 : 128;
    const int ci = (l==0) ? 512 : ((l==1) ? 256 : 128);
    float* gCur = gbufs[l&1];
    float* oCur = obufs[l&1];

    if (l==0){
      for (int d=0;d<ND;d++)
        k_gemm<<<dim3(256/64, NN/64, 1), 256, 0, stream>>>(
          dims_in[d], 0, convW[0] + (size_t)d*512*256, 0, nullptr, 0,
          hbuf + (size_t)d*NN*256, 0, NN, 512, 256);
    } else {
      k_gemm<<<dim3(co/64, NN/64, ND), 256, 0, stream>>>(
        gPrev, (long long)NN*ci, convW[l], (long long)ci*co, nullptr, 0,
        hbuf, (long long)NN*co, NN, ci, co);
    }

    k_layerinit<<<ND, 256, 0, stream>>>(bnd, ctrlU, ctrlI);
    k_agg<<<dim3(NN, ND), co, 0, stream>>>(hbuf, gCur, convb[l], csr_base, csr_psrc,
                                           csr_coef, selfw, co);
    k_rownorm<<<dim3(NN, ND), 256, 0, stream>>>(gCur, xnbuf, co);
    k_prep<<<dim3(NN/8, ND), co, 0, stream>>>(xnbuf, xph, xpl, co);
    k_colsum<<<dim3(co/64, ND), 256, 0, stream>>>(xnbuf, sbuf, co);
    k_adot<<<dim3(NN/8, ND), 512, 0, stream>>>(xnbuf, sbuf, abuf, ctrlU, co);
    k_gramC<<<dim3((co/32)*(co/32), ND), 256, 0, stream>>>(xnbuf, Cbuf, co);

    // power iteration: 33 iterations, 2 micro-kernels each (z then y)
    k_pw_init<<<ND, 1024, 0, stream>>>(vpow, scACC);
    if (l==0){
      for (int it=0; it<33; it++){
        const int sp = it & 1, sc = sp ^ 1;
        k_pw_z<256><<<dim3(16, ND), 256, 0, stream>>>(xnbuf, vpow, zpartG, scACC, sc);
        k_pw_y<256><<<dim3(16, ND), 256, 0, stream>>>(xnbuf, abuf, ctrlU, zpartG, vpow, scACC, sp, sc);
      }
    } else {
      for (int it=0; it<33; it++){
        const int sp = it & 1, sc = sp ^ 1;
        k_pw_z<128><<<dim3(16, ND), 128, 0, stream>>>(xnbuf, vpow, zpartG, scACC, sc);
        k_pw_y<128><<<dim3(16, ND), 256, 0, stream>>>(xnbuf, abuf, ctrlU, zpartG, vpow, scACC, sp, sc);
      }
    }
    k_pw_fin<<<1, 64, 0, stream>>>(scACC, thB, 1);

    k_bounds<<<ND, 256, 0, stream>>>(Cbuf, ctrlU, thB, ctrlF, ctrlI, co);

    if (l==0){
      k_eval<256,640,1><<<dim3(MAXB1+1, ND), 640, SMEM_D(256), stream>>>(xph, xpl, abuf, ctrlF, ctrlI, nu1, tus1);
      k_sel<<<dim3((MAXB1+255)/256, ND), 256, 0, stream>>>(nu1, ctrlI, binSel, fineBins);
      k_fill<<<dim3((NBF+255)/256, ND), 256, 0, stream>>>(nu1, tus1, binSel, ctrlF, ctrlI, nuF, tusF);
      k_evalF<256,640,1><<<dim3(NFMAX*(SUBD-1), ND), 640, SMEM_D(256), stream>>>(xph, xpl, abuf, ctrlF, ctrlI, fineBins, nuF, tusF);
      k_runs<<<dim3((NBF+255)/256, ND), 256, 0, stream>>>(nuF, tusF, ctrlI, runP, runB, bnd);
      k_probe<256,640,1><<<dim3(MAXRUN*2*NPB, ND), 640, SMEM_D(256), stream>>>(xph, xpl, abuf, ctrlI, runP, runB, nuP, tP);
      k_decide<<<ND, 256, 0, stream>>>(ctrlI, runP, runB, nuP, tP, bnd);
    } else {
      k_eval<128,192,4><<<dim3(MAXB1+1, ND), 192, SMEM_D(128), stream>>>(xph, xpl, abuf, ctrlF, ctrlI, nu1, tus1);
      k_sel<<<dim3((MAXB1+255)/256, ND), 256, 0, stream>>>(nu1, ctrlI, binSel, fineBins);
      k_fill<<<dim3((NBF+255)/256, ND), 256, 0, stream>>>(nu1, tus1, binSel, ctrlF, ctrlI, nuF, tusF);
      k_evalF<128,192,4><<<dim3(NFMAX*(SUBD-1), ND), 192, SMEM_D(128), stream>>>(xph, xpl, abuf, ctrlF, ctrlI, fineBins, nuF, tusF);
      k_runs<<<dim3((NBF+255)/256, ND), 256, 0, stream>>>(nuF, tusF, ctrlI, runP, runB, bnd);
      k_probe<128,192,4><<<dim3(MAXRUN*2*NPB, ND), 192, SMEM_D(128), stream>>>(xph, xpl, abuf, ctrlI, runP, runB, nuP, tP);
      k_decide<<<ND, 256, 0, stream>>>(ctrlI, runP, runB, nuP, tP, bnd);
    }

    k_flags<<<ND, 64, 0, stream>>>(bnd, flagsA, cstart, ctrlI);
    k_cavg<<<dim3(128, ND), 256, 0, stream>>>(gCur, cstart, ctrlI, cavg, co);
    k_clin<<<dim3(128, ND), 256, 0, stream>>>(cavg, linW[l], linb[l], xnbuf, ctrlI, co);

    const float* firPtr;
    if (l==0){
      for (int d=0;d<ND;d++)
        k_gemm<<<dim3(256/64, NN/64, 1), 256, 0, stream>>>(
          dims_in[d], 0, ch1W, 0, ch1b, 0, hbuf + (size_t)d*NN*256, 0, NN, 512, 256);
      firPtr = hbuf;
    } else if (l==1){
      k_gemm<<<dim3(128/64, NN/64, ND), 256, 0, stream>>>(
        oPrev, (long long)NN*256, ch2W, 0, ch2b, 0, hbuf, (long long)NN*128, NN, 256, 128);
      firPtr = hbuf;
    } else {
      firPtr = oPrev;
    }

    k_out<<<dim3(NN, ND), co, 0, stream>>>(firPtr, xnbuf, flagsA, ksv, oCur, co);

    gPrev = gCur; oPrev = oCur;
  }

  k_final<<<NN, 128, 0, stream>>>(oPrev, dimw, (float*)d_out);
}